// Round 1
// baseline (1741.428 us; speedup 1.0000x reference)
//
#include <hip/hip_runtime.h>
#include <cstddef>
#include <cstdint>

// ---------------------------------------------------------------------------
// SimpleHAN on MI355X — round 0: correctness-first full pipeline.
//   proj GEMM -> {tut, tdt} x 2 GATConv layers (CSR-by-dst, wave-per-node
//   softmax aggregation) -> semantic combine -> cls MLP.
// All fp32 vector math (no fp32 MFMA on CDNA4). No atomics in fp accumulation.
// ---------------------------------------------------------------------------

#define HID        256
#define HEADS      8
#define HEAD_DIM   32
#define NEG_SLOPE  0.2f

// ---------------------------- SGEMM (64x64 tile) ---------------------------
// C[M,N] = A[M,K] @ B[K,N] (+bias) (+relu). K % 16 == 0, N % 64 == 0.
__global__ __launch_bounds__(256) void sgemm_kernel(
    const float* __restrict__ A, const float* __restrict__ B,
    const float* __restrict__ bias, float* __restrict__ C,
    int M, int N, int K, int act)
{
    __shared__ float As[16][64];   // [k][m]
    __shared__ float Bs[16][64];   // [k][n]

    const int tx = threadIdx.x & 15;   // n dir
    const int ty = threadIdx.x >> 4;   // m dir
    const int m0 = blockIdx.y * 64;
    const int n0 = blockIdx.x * 64;

    const int lm  = threadIdx.x >> 2;        // 0..63  A-load row
    const int lk4 = (threadIdx.x & 3) * 4;   // 0,4,8,12
    const int lr  = threadIdx.x >> 4;        // 0..15  B-load row
    const int lc4 = (threadIdx.x & 15) * 4;

    float acc[4][4];
    #pragma unroll
    for (int i = 0; i < 4; ++i)
        #pragma unroll
        for (int j = 0; j < 4; ++j) acc[i][j] = 0.f;

    for (int k0 = 0; k0 < K; k0 += 16) {
        float4 av = make_float4(0.f, 0.f, 0.f, 0.f);
        if (m0 + lm < M)
            av = *reinterpret_cast<const float4*>(&A[(size_t)(m0 + lm) * K + k0 + lk4]);
        As[lk4 + 0][lm] = av.x;
        As[lk4 + 1][lm] = av.y;
        As[lk4 + 2][lm] = av.z;
        As[lk4 + 3][lm] = av.w;

        float4 bv = *reinterpret_cast<const float4*>(&B[(size_t)(k0 + lr) * N + n0 + lc4]);
        *reinterpret_cast<float4*>(&Bs[lr][lc4]) = bv;
        __syncthreads();

        #pragma unroll
        for (int k = 0; k < 16; ++k) {
            float a[4], b[4];
            #pragma unroll
            for (int i = 0; i < 4; ++i) a[i] = As[k][ty * 4 + i];
            #pragma unroll
            for (int j = 0; j < 4; ++j) b[j] = Bs[k][tx * 4 + j];
            #pragma unroll
            for (int i = 0; i < 4; ++i)
                #pragma unroll
                for (int j = 0; j < 4; ++j) acc[i][j] += a[i] * b[j];
        }
        __syncthreads();
    }

    float4 bv = make_float4(0.f, 0.f, 0.f, 0.f);
    if (bias) bv = *reinterpret_cast<const float4*>(&bias[n0 + tx * 4]);
    #pragma unroll
    for (int i = 0; i < 4; ++i) {
        int row = m0 + ty * 4 + i;
        if (row < M) {
            float4 o;
            o.x = acc[i][0] + bv.x;
            o.y = acc[i][1] + bv.y;
            o.z = acc[i][2] + bv.z;
            o.w = acc[i][3] + bv.w;
            if (act == 1) {
                o.x = fmaxf(o.x, 0.f); o.y = fmaxf(o.y, 0.f);
                o.z = fmaxf(o.z, 0.f); o.w = fmaxf(o.w, 0.f);
            }
            *reinterpret_cast<float4*>(&C[(size_t)row * N + n0 + tx * 4]) = o;
        }
    }
}

// ------------------------- attention dot products --------------------------
// a_src[n,h] = sum_d hW[n,h*32+d]*att_src[h,d]; same for a_dst. Wave per node.
__global__ __launch_bounds__(256) void att_kernel(
    const float* __restrict__ hW,
    const float* __restrict__ att_src, const float* __restrict__ att_dst,
    float* __restrict__ a_src, float* __restrict__ a_dst, int n_nodes)
{
    const int wave = threadIdx.x >> 6;
    const int lane = threadIdx.x & 63;
    const int n = blockIdx.x * 4 + wave;
    if (n >= n_nodes) return;

    float4 hv = *reinterpret_cast<const float4*>(&hW[(size_t)n * HID + lane * 4]);
    float4 s4 = *reinterpret_cast<const float4*>(&att_src[lane * 4]);
    float4 d4 = *reinterpret_cast<const float4*>(&att_dst[lane * 4]);
    float ps = hv.x * s4.x + hv.y * s4.y + hv.z * s4.z + hv.w * s4.w;
    float pd = hv.x * d4.x + hv.y * d4.y + hv.z * d4.z + hv.w * d4.w;
    #pragma unroll
    for (int off = 1; off < 8; off <<= 1) {
        ps += __shfl_xor(ps, off);
        pd += __shfl_xor(pd, off);
    }
    if ((lane & 7) == 0) {
        a_src[n * HEADS + (lane >> 3)] = ps;
        a_dst[n * HEADS + (lane >> 3)] = pd;
    }
}

// --------------------- GAT softmax + aggregation (CSR) ----------------------
// One wave per destination node. Phase 1: online max/sum-exp per head
// (8 neighbor slots x 8 heads across 64 lanes). Phase 2: alpha-weighted
// gather of hW[src] with fused bias + ELU.
__global__ __launch_bounds__(256) void gat_kernel(
    const float* __restrict__ hW,
    const float* __restrict__ a_src, const float* __restrict__ a_dst,
    const int* __restrict__ row_ptr, const int* __restrict__ adj,
    const float* __restrict__ bias, float* __restrict__ out, int n_nodes)
{
    const int wave = threadIdx.x >> 6;
    const int lane = threadIdx.x & 63;
    const int n = blockIdx.x * 4 + wave;
    if (n >= n_nodes) return;

    const int beg = row_ptr[n];
    const int end = row_ptr[n + 1];

    // phase 1: lane handles head h1 = lane&7, neighbor slot = lane>>3
    const int h1 = lane & 7;
    const float adst1 = a_dst[n * HEADS + h1];
    float m = -INFINITY, s = 0.f;
    for (int j = beg + (lane >> 3); j < end; j += 8) {
        float e = a_src[adj[j] * HEADS + h1] + adst1;
        e = (e > 0.f) ? e : NEG_SLOPE * e;
        float mn = fmaxf(m, e);
        float t = (m > -INFINITY) ? s * __expf(m - mn) : 0.f;
        s = t + __expf(e - mn);
        m = mn;
    }
    // butterfly merge across the 8 slots (same head: lanes differ in bits 3..5)
    #pragma unroll
    for (int off = 8; off < 64; off <<= 1) {
        float mo = __shfl_xor(m, off);
        float so = __shfl_xor(s, off);
        float mn = fmaxf(m, mo);
        float t1 = (m  > -INFINITY) ? s  * __expf(m  - mn) : 0.f;
        float t2 = (mo > -INFINITY) ? so * __expf(mo - mn) : 0.f;
        s = t1 + t2;
        m = mn;
    }

    // redistribute to dim layout: lane covers dims 4*lane..4*lane+3, head = lane>>3
    const int h2 = lane >> 3;
    const float mh  = __shfl(m, h2);          // lane h2 holds head h2's result
    const float sh  = __shfl(s, h2);
    const float inv = 1.f / (sh + 1e-16f);
    const float adst2 = a_dst[n * HEADS + h2];

    float4 acc = make_float4(0.f, 0.f, 0.f, 0.f);
    for (int j = beg; j < end; ++j) {
        int src = adj[j];
        float e = a_src[src * HEADS + h2] + adst2;
        e = (e > 0.f) ? e : NEG_SLOPE * e;
        float alpha = __expf(e - mh) * inv;
        float4 hv = *reinterpret_cast<const float4*>(&hW[(size_t)src * HID + lane * 4]);
        acc.x += alpha * hv.x;
        acc.y += alpha * hv.y;
        acc.z += alpha * hv.z;
        acc.w += alpha * hv.w;
    }

    float4 bv = *reinterpret_cast<const float4*>(&bias[lane * 4]);
    float4 o;
    o.x = acc.x + bv.x; o.y = acc.y + bv.y; o.z = acc.z + bv.z; o.w = acc.w + bv.w;
    // ELU
    o.x = (o.x > 0.f) ? o.x : expm1f(o.x);
    o.y = (o.y > 0.f) ? o.y : expm1f(o.y);
    o.z = (o.z > 0.f) ? o.z : expm1f(o.z);
    o.w = (o.w > 0.f) ? o.w : expm1f(o.w);
    *reinterpret_cast<float4*>(&out[(size_t)n * HID + lane * 4]) = o;
}

// ------------------------------- CSR build ---------------------------------
__global__ void deg_count_kernel(const int* __restrict__ dst, int* __restrict__ deg, int E)
{
    for (int e = blockIdx.x * blockDim.x + threadIdx.x; e < E; e += gridDim.x * blockDim.x)
        atomicAdd(&deg[dst[e]], 1);
}

// exclusive scan of (deg[i]+1) into row_ptr (single block, chunked)
__global__ __launch_bounds__(256) void scan_rowptr_kernel(
    const int* __restrict__ deg, int* __restrict__ row_ptr, int n)
{
    __shared__ int sm[256];
    __shared__ int carry;
    const int tid = threadIdx.x;
    if (tid == 0) { carry = 0; row_ptr[0] = 0; }
    __syncthreads();
    for (int base = 0; base < n; base += 256) {
        int i = base + tid;
        int v = (i < n) ? (deg[i] + 1) : 0;   // +1 self loop
        sm[tid] = v;
        __syncthreads();
        #pragma unroll
        for (int off = 1; off < 256; off <<= 1) {
            int t = (tid >= off) ? sm[tid - off] : 0;
            __syncthreads();
            sm[tid] += t;
            __syncthreads();
        }
        if (i < n) row_ptr[i + 1] = carry + sm[tid];
        __syncthreads();
        if (tid == 255) carry += sm[255];
        __syncthreads();
    }
}

__global__ void init_cursor_selfloop_kernel(
    const int* __restrict__ row_ptr, int* __restrict__ cursor,
    int* __restrict__ adj, int n)
{
    int i = blockIdx.x * blockDim.x + threadIdx.x;
    if (i < n) {
        int p = row_ptr[i];
        adj[p] = i;            // self loop first
        cursor[i] = p + 1;
    }
}

__global__ void edge_scatter_kernel(
    const int* __restrict__ src, const int* __restrict__ dst,
    int* __restrict__ cursor, int* __restrict__ adj, int E)
{
    for (int e = blockIdx.x * blockDim.x + threadIdx.x; e < E; e += gridDim.x * blockDim.x) {
        int pos = atomicAdd(&cursor[dst[e]], 1);
        adj[pos] = src[e];
    }
}

// ------------------------- combine + classifier ----------------------------
__global__ void combine_kernel(const float* __restrict__ a, const float* __restrict__ b,
                               const float* __restrict__ sem, float* __restrict__ z,
                               int count4)
{
    float e0 = __expf(sem[0]);
    float e1 = __expf(sem[1]);
    float w0 = e0 / (e0 + e1);
    float w1 = e1 / (e0 + e1);
    for (int i = blockIdx.x * blockDim.x + threadIdx.x; i < count4; i += gridDim.x * blockDim.x) {
        float4 va = reinterpret_cast<const float4*>(a)[i];
        float4 vb = reinterpret_cast<const float4*>(b)[i];
        float4 o;
        o.x = w0 * va.x + w1 * vb.x;
        o.y = w0 * va.y + w1 * vb.y;
        o.z = w0 * va.z + w1 * vb.z;
        o.w = w0 * va.w + w1 * vb.w;
        reinterpret_cast<float4*>(z)[i] = o;
    }
}

// logits[n, 0:2] = hc[n, 0:128] @ W2[128,2] + b2. Wave per node.
__global__ __launch_bounds__(256) void cls2_kernel(
    const float* __restrict__ hc, const float* __restrict__ W2,
    const float* __restrict__ b2, float* __restrict__ out, int n_nodes)
{
    const int wave = threadIdx.x >> 6;
    const int lane = threadIdx.x & 63;
    const int n = blockIdx.x * 4 + wave;
    if (n >= n_nodes) return;
    float h0 = hc[(size_t)n * 128 + lane];
    float h1 = hc[(size_t)n * 128 + 64 + lane];
    float p0 = h0 * W2[lane * 2 + 0] + h1 * W2[(64 + lane) * 2 + 0];
    float p1 = h0 * W2[lane * 2 + 1] + h1 * W2[(64 + lane) * 2 + 1];
    #pragma unroll
    for (int off = 1; off < 64; off <<= 1) {
        p0 += __shfl_xor(p0, off);
        p1 += __shfl_xor(p1, off);
    }
    if (lane == 0) {
        out[(size_t)n * 2 + 0] = p0 + b2[0];
        out[(size_t)n * 2 + 1] = p1 + b2[1];
    }
}

// ---------------------------------------------------------------------------
extern "C" void kernel_launch(void* const* d_in, const int* in_sizes, int n_in,
                              void* d_out, int out_size, void* d_ws, size_t ws_size,
                              hipStream_t stream)
{
    const float* x        = (const float*)d_in[0];
    const int*   tut_ei   = (const int*)d_in[1];
    const int*   tdt_ei   = (const int*)d_in[2];
    const float* proj_W   = (const float*)d_in[3];
    const float* proj_b   = (const float*)d_in[4];
    const float* tut_W    = (const float*)d_in[5];
    const float* tut_asrc = (const float*)d_in[6];
    const float* tut_adst = (const float*)d_in[7];
    const float* tut_bias = (const float*)d_in[8];
    const float* tdt_W    = (const float*)d_in[9];
    const float* tdt_asrc = (const float*)d_in[10];
    const float* tdt_adst = (const float*)d_in[11];
    const float* tdt_bias = (const float*)d_in[12];
    const float* sem_att  = (const float*)d_in[13];
    const float* cls_W1   = (const float*)d_in[14];
    const float* cls_b1   = (const float*)d_in[15];
    const float* cls_W2   = (const float*)d_in[16];
    const float* cls_b2   = (const float*)d_in[17];

    const int IN_CH = 128;
    const int N = in_sizes[0] / IN_CH;     // 50000
    const int E = in_sizes[1] / 2;         // 800000

    // ------------------------ workspace layout ------------------------
    char* base = (char*)d_ws;
    size_t off = 0;
    auto alloc = [&](size_t bytes) -> void* {
        void* p = base + off;
        off = (off + bytes + 255) & ~(size_t)255;
        return p;
    };
    float* h0    = (float*)alloc((size_t)N * HID * sizeof(float));
    float* bufA  = (float*)alloc((size_t)N * HID * sizeof(float));
    float* bufB  = (float*)alloc((size_t)N * HID * sizeof(float));
    float* bufT  = (float*)alloc((size_t)N * HID * sizeof(float));
    float* a_src = (float*)alloc((size_t)N * HEADS * sizeof(float));
    float* a_dst = (float*)alloc((size_t)N * HEADS * sizeof(float));
    int* rp_tut  = (int*)alloc((size_t)(N + 1) * sizeof(int));
    int* adj_tut = (int*)alloc((size_t)(E + N) * sizeof(int));
    int* rp_tdt  = (int*)alloc((size_t)(N + 1) * sizeof(int));
    int* adj_tdt = (int*)alloc((size_t)(E + N) * sizeof(int));
    int* cursor  = (int*)alloc((size_t)N * sizeof(int));    // also used as deg
    (void)ws_size; (void)n_in; (void)out_size;

    const int nodeBlocks = (N + 3) / 4;

    // ---------------------------- CSR build ---------------------------
    auto build_csr = [&](const int* ei, int* row_ptr, int* adj) {
        hipMemsetAsync(cursor, 0, (size_t)N * sizeof(int), stream);
        deg_count_kernel<<<1024, 256, 0, stream>>>(ei + E, cursor, E);
        scan_rowptr_kernel<<<1, 256, 0, stream>>>(cursor, row_ptr, N);
        init_cursor_selfloop_kernel<<<(N + 255) / 256, 256, 0, stream>>>(row_ptr, cursor, adj, N);
        edge_scatter_kernel<<<1024, 256, 0, stream>>>(ei, ei + E, cursor, adj, E);
    };
    build_csr(tut_ei, rp_tut, adj_tut);
    build_csr(tdt_ei, rp_tdt, adj_tdt);

    // ------------------------------ proj ------------------------------
    {
        dim3 g(HID / 64, (N + 63) / 64);
        sgemm_kernel<<<g, 256, 0, stream>>>(x, proj_W, proj_b, h0, N, HID, IN_CH, 0);
    }

    // ---------------------------- GAT layers --------------------------
    auto run_gat = [&](const float* in, const float* W, const float* asrc_w,
                       const float* adst_w, const float* bias,
                       const int* row_ptr, const int* adj, float* outbuf) {
        dim3 g(HID / 64, (N + 63) / 64);
        sgemm_kernel<<<g, 256, 0, stream>>>(in, W, nullptr, bufA, N, HID, HID, 0);
        att_kernel<<<nodeBlocks, 256, 0, stream>>>(bufA, asrc_w, adst_w, a_src, a_dst, N);
        gat_kernel<<<nodeBlocks, 256, 0, stream>>>(bufA, a_src, a_dst, row_ptr, adj, bias, outbuf, N);
    };

    const int WS = HID * HID;   // weight stride per layer
    const int AS = HEADS * HEAD_DIM;

    // TUT branch: h0 -> bufB -> bufT
    run_gat(h0,   tut_W,      tut_asrc,      tut_adst,      tut_bias,       rp_tut, adj_tut, bufB);
    run_gat(bufB, tut_W + WS, tut_asrc + AS, tut_adst + AS, tut_bias + HID, rp_tut, adj_tut, bufT);
    // TDT branch: h0 -> bufB -> bufB (gemm consumes bufB into bufA first)
    run_gat(h0,   tdt_W,      tdt_asrc,      tdt_adst,      tdt_bias,       rp_tdt, adj_tdt, bufB);
    run_gat(bufB, tdt_W + WS, tdt_asrc + AS, tdt_adst + AS, tdt_bias + HID, rp_tdt, adj_tdt, bufB);

    // ------------------------- combine + classifier -------------------
    {
        int count4 = N * HID / 4;
        combine_kernel<<<2048, 256, 0, stream>>>(bufT, bufB, sem_att, bufA, count4);
        dim3 g(128 / 64, (N + 63) / 64);
        sgemm_kernel<<<g, 256, 0, stream>>>(bufA, cls_W1, cls_b1, h0, N, 128, HID, 1);
        cls2_kernel<<<nodeBlocks, 256, 0, stream>>>(h0, cls_W2, cls_b2, (float*)d_out, N);
    }
}

// Round 2
// 1318.449 us; speedup vs baseline: 1.3208x; 1.3208x over previous
//
#include <hip/hip_runtime.h>
#include <cstddef>
#include <cstdint>

// ---------------------------------------------------------------------------
// SimpleHAN on MI355X — round 1:
//   - parallel hierarchical CSR scan (was: 212us single-block scan x2)
//   - SGEMM 128x64 tile, 8x4 per-thread register blocking (VALU-bound)
// ---------------------------------------------------------------------------

#define HID        256
#define HEADS      8
#define HEAD_DIM   32
#define NEG_SLOPE  0.2f

// ---------------------------- SGEMM (128x64 tile) --------------------------
// C[M,N] = A[M,K] @ B[K,N] (+bias) (+relu). K%16==0, N%64==0.
// 256 threads; per-thread 8x4 acc; BK=16.
__global__ __launch_bounds__(256) void sgemm_kernel(
    const float* __restrict__ A, const float* __restrict__ B,
    const float* __restrict__ bias, float* __restrict__ C,
    int M, int N, int K, int act)
{
    __shared__ float As[16][128];  // [k][m]  8 KB
    __shared__ float Bs[16][64];   // [k][n]  4 KB

    const int tid = threadIdx.x;
    const int tx = tid & 15;       // n dir (4 cols each)
    const int ty = tid >> 4;       // m dir (8 rows each)
    const int m0 = blockIdx.y * 128;
    const int n0 = blockIdx.x * 64;

    // A loader: thread -> row lm = tid>>1 (0..127), k offset lk = (tid&1)*8
    const int lm = tid >> 1;
    const int lk = (tid & 1) * 8;
    // B loader: row lr = tid>>4 (0..15), col lc4 = (tid&15)*4
    const int lr = tid >> 4;
    const int lc4 = (tid & 15) * 4;

    float acc[8][4];
    #pragma unroll
    for (int i = 0; i < 8; ++i)
        #pragma unroll
        for (int j = 0; j < 4; ++j) acc[i][j] = 0.f;

    for (int k0 = 0; k0 < K; k0 += 16) {
        float4 a0 = make_float4(0.f, 0.f, 0.f, 0.f);
        float4 a1 = make_float4(0.f, 0.f, 0.f, 0.f);
        if (m0 + lm < M) {
            const float* ap = &A[(size_t)(m0 + lm) * K + k0 + lk];
            a0 = *reinterpret_cast<const float4*>(ap);
            a1 = *reinterpret_cast<const float4*>(ap + 4);
        }
        As[lk + 0][lm] = a0.x; As[lk + 1][lm] = a0.y;
        As[lk + 2][lm] = a0.z; As[lk + 3][lm] = a0.w;
        As[lk + 4][lm] = a1.x; As[lk + 5][lm] = a1.y;
        As[lk + 6][lm] = a1.z; As[lk + 7][lm] = a1.w;

        float4 bv = *reinterpret_cast<const float4*>(&B[(size_t)(k0 + lr) * N + n0 + lc4]);
        *reinterpret_cast<float4*>(&Bs[lr][lc4]) = bv;
        __syncthreads();

        #pragma unroll
        for (int k = 0; k < 16; ++k) {
            float4 av0 = *reinterpret_cast<const float4*>(&As[k][ty * 8]);
            float4 av1 = *reinterpret_cast<const float4*>(&As[k][ty * 8 + 4]);
            float4 bv4 = *reinterpret_cast<const float4*>(&Bs[k][tx * 4]);
            float a[8] = {av0.x, av0.y, av0.z, av0.w, av1.x, av1.y, av1.z, av1.w};
            float b[4] = {bv4.x, bv4.y, bv4.z, bv4.w};
            #pragma unroll
            for (int i = 0; i < 8; ++i)
                #pragma unroll
                for (int j = 0; j < 4; ++j) acc[i][j] += a[i] * b[j];
        }
        __syncthreads();
    }

    float4 bv = make_float4(0.f, 0.f, 0.f, 0.f);
    if (bias) bv = *reinterpret_cast<const float4*>(&bias[n0 + tx * 4]);
    #pragma unroll
    for (int i = 0; i < 8; ++i) {
        int row = m0 + ty * 8 + i;
        if (row < M) {
            float4 o;
            o.x = acc[i][0] + bv.x;
            o.y = acc[i][1] + bv.y;
            o.z = acc[i][2] + bv.z;
            o.w = acc[i][3] + bv.w;
            if (act == 1) {
                o.x = fmaxf(o.x, 0.f); o.y = fmaxf(o.y, 0.f);
                o.z = fmaxf(o.z, 0.f); o.w = fmaxf(o.w, 0.f);
            }
            *reinterpret_cast<float4*>(&C[(size_t)row * N + n0 + tx * 4]) = o;
        }
    }
}

// ------------------------- attention dot products --------------------------
__global__ __launch_bounds__(256) void att_kernel(
    const float* __restrict__ hW,
    const float* __restrict__ att_src, const float* __restrict__ att_dst,
    float* __restrict__ a_src, float* __restrict__ a_dst, int n_nodes)
{
    const int wave = threadIdx.x >> 6;
    const int lane = threadIdx.x & 63;
    const int n = blockIdx.x * 4 + wave;
    if (n >= n_nodes) return;

    float4 hv = *reinterpret_cast<const float4*>(&hW[(size_t)n * HID + lane * 4]);
    float4 s4 = *reinterpret_cast<const float4*>(&att_src[lane * 4]);
    float4 d4 = *reinterpret_cast<const float4*>(&att_dst[lane * 4]);
    float ps = hv.x * s4.x + hv.y * s4.y + hv.z * s4.z + hv.w * s4.w;
    float pd = hv.x * d4.x + hv.y * d4.y + hv.z * d4.z + hv.w * d4.w;
    #pragma unroll
    for (int off = 1; off < 8; off <<= 1) {
        ps += __shfl_xor(ps, off);
        pd += __shfl_xor(pd, off);
    }
    if ((lane & 7) == 0) {
        a_src[n * HEADS + (lane >> 3)] = ps;
        a_dst[n * HEADS + (lane >> 3)] = pd;
    }
}

// --------------------- GAT softmax + aggregation (CSR) ----------------------
__global__ __launch_bounds__(256) void gat_kernel(
    const float* __restrict__ hW,
    const float* __restrict__ a_src, const float* __restrict__ a_dst,
    const int* __restrict__ row_ptr, const int* __restrict__ adj,
    const float* __restrict__ bias, float* __restrict__ out, int n_nodes)
{
    const int wave = threadIdx.x >> 6;
    const int lane = threadIdx.x & 63;
    const int n = blockIdx.x * 4 + wave;
    if (n >= n_nodes) return;

    const int beg = row_ptr[n];
    const int end = row_ptr[n + 1];

    // phase 1: lane handles head h1 = lane&7, neighbor slot = lane>>3
    const int h1 = lane & 7;
    const float adst1 = a_dst[n * HEADS + h1];
    float m = -INFINITY, s = 0.f;
    for (int j = beg + (lane >> 3); j < end; j += 8) {
        float e = a_src[adj[j] * HEADS + h1] + adst1;
        e = (e > 0.f) ? e : NEG_SLOPE * e;
        float mn = fmaxf(m, e);
        float t = (m > -INFINITY) ? s * __expf(m - mn) : 0.f;
        s = t + __expf(e - mn);
        m = mn;
    }
    #pragma unroll
    for (int off = 8; off < 64; off <<= 1) {
        float mo = __shfl_xor(m, off);
        float so = __shfl_xor(s, off);
        float mn = fmaxf(m, mo);
        float t1 = (m  > -INFINITY) ? s  * __expf(m  - mn) : 0.f;
        float t2 = (mo > -INFINITY) ? so * __expf(mo - mn) : 0.f;
        s = t1 + t2;
        m = mn;
    }

    const int h2 = lane >> 3;
    const float mh  = __shfl(m, h2);
    const float sh  = __shfl(s, h2);
    const float inv = 1.f / (sh + 1e-16f);
    const float adst2 = a_dst[n * HEADS + h2];

    float4 acc = make_float4(0.f, 0.f, 0.f, 0.f);
    for (int j = beg; j < end; ++j) {
        int src = adj[j];
        float e = a_src[src * HEADS + h2] + adst2;
        e = (e > 0.f) ? e : NEG_SLOPE * e;
        float alpha = __expf(e - mh) * inv;
        float4 hv = *reinterpret_cast<const float4*>(&hW[(size_t)src * HID + lane * 4]);
        acc.x += alpha * hv.x;
        acc.y += alpha * hv.y;
        acc.z += alpha * hv.z;
        acc.w += alpha * hv.w;
    }

    float4 bv = *reinterpret_cast<const float4*>(&bias[lane * 4]);
    float4 o;
    o.x = acc.x + bv.x; o.y = acc.y + bv.y; o.z = acc.z + bv.z; o.w = acc.w + bv.w;
    o.x = (o.x > 0.f) ? o.x : expm1f(o.x);
    o.y = (o.y > 0.f) ? o.y : expm1f(o.y);
    o.z = (o.z > 0.f) ? o.z : expm1f(o.z);
    o.w = (o.w > 0.f) ? o.w : expm1f(o.w);
    *reinterpret_cast<float4*>(&out[(size_t)n * HID + lane * 4]) = o;
}

// ------------------------------- CSR build ---------------------------------
__global__ void deg_count_kernel(const int* __restrict__ dst, int* __restrict__ deg, int E)
{
    for (int e = blockIdx.x * blockDim.x + threadIdx.x; e < E; e += gridDim.x * blockDim.x)
        atomicAdd(&deg[dst[e]], 1);
}

// --- hierarchical exclusive scan of (deg[i]+1) into row_ptr[0..n] ---
// stage 1: 1024 elems/block; per-block inclusive scan written to row_ptr[i+1]
//          (no carry), block totals to blockSums.
__global__ __launch_bounds__(256) void scan_block_kernel(
    const int* __restrict__ deg, int* __restrict__ row_ptr,
    int* __restrict__ blockSums, int n)
{
    __shared__ int sm[256];
    const int tid = threadIdx.x;
    const int i0 = blockIdx.x * 1024 + tid * 4;
    int v0 = (i0 + 0 < n) ? deg[i0 + 0] + 1 : 0;
    int v1 = (i0 + 1 < n) ? deg[i0 + 1] + 1 : 0;
    int v2 = (i0 + 2 < n) ? deg[i0 + 2] + 1 : 0;
    int v3 = (i0 + 3 < n) ? deg[i0 + 3] + 1 : 0;
    int s1 = v0 + v1, s2 = s1 + v2, s3 = s2 + v3;
    sm[tid] = s3;
    __syncthreads();
    #pragma unroll
    for (int off = 1; off < 256; off <<= 1) {
        int t = (tid >= off) ? sm[tid - off] : 0;
        __syncthreads();
        sm[tid] += t;
        __syncthreads();
    }
    int prev = (tid > 0) ? sm[tid - 1] : 0;
    if (tid == 255) blockSums[blockIdx.x] = sm[255];
    if (i0 + 0 < n) row_ptr[i0 + 1] = prev + v0;
    if (i0 + 1 < n) row_ptr[i0 + 2] = prev + s1;
    if (i0 + 2 < n) row_ptr[i0 + 3] = prev + s2;
    if (i0 + 3 < n) row_ptr[i0 + 4] = prev + s3;
}

// stage 2: inclusive scan of block sums (nb <= 64), one wave
__global__ void scan_sums_kernel(int* __restrict__ blockSums, int nb)
{
    const int lane = threadIdx.x;
    int v = (lane < nb) ? blockSums[lane] : 0;
    #pragma unroll
    for (int off = 1; off < 64; off <<= 1) {
        int t = __shfl_up(v, off);
        if (lane >= off) v += t;
    }
    if (lane < nb) blockSums[lane] = v;
}

// stage 3: add carries; set row_ptr[0]=0
__global__ __launch_bounds__(256) void scan_fixup_kernel(
    int* __restrict__ row_ptr, const int* __restrict__ blockSums, int n)
{
    int i = blockIdx.x * blockDim.x + threadIdx.x;
    if (i == 0) row_ptr[0] = 0;
    if (i < n) {
        int b = i >> 10;
        if (b > 0) row_ptr[i + 1] += blockSums[b - 1];
    }
}

__global__ void init_cursor_selfloop_kernel(
    const int* __restrict__ row_ptr, int* __restrict__ cursor,
    int* __restrict__ adj, int n)
{
    int i = blockIdx.x * blockDim.x + threadIdx.x;
    if (i < n) {
        int p = row_ptr[i];
        adj[p] = i;            // self loop first
        cursor[i] = p + 1;
    }
}

__global__ void edge_scatter_kernel(
    const int* __restrict__ src, const int* __restrict__ dst,
    int* __restrict__ cursor, int* __restrict__ adj, int E)
{
    for (int e = blockIdx.x * blockDim.x + threadIdx.x; e < E; e += gridDim.x * blockDim.x) {
        int pos = atomicAdd(&cursor[dst[e]], 1);
        adj[pos] = src[e];
    }
}

// ------------------------- combine + classifier ----------------------------
__global__ void combine_kernel(const float* __restrict__ a, const float* __restrict__ b,
                               const float* __restrict__ sem, float* __restrict__ z,
                               int count4)
{
    float e0 = __expf(sem[0]);
    float e1 = __expf(sem[1]);
    float w0 = e0 / (e0 + e1);
    float w1 = e1 / (e0 + e1);
    for (int i = blockIdx.x * blockDim.x + threadIdx.x; i < count4; i += gridDim.x * blockDim.x) {
        float4 va = reinterpret_cast<const float4*>(a)[i];
        float4 vb = reinterpret_cast<const float4*>(b)[i];
        float4 o;
        o.x = w0 * va.x + w1 * vb.x;
        o.y = w0 * va.y + w1 * vb.y;
        o.z = w0 * va.z + w1 * vb.z;
        o.w = w0 * va.w + w1 * vb.w;
        reinterpret_cast<float4*>(z)[i] = o;
    }
}

__global__ __launch_bounds__(256) void cls2_kernel(
    const float* __restrict__ hc, const float* __restrict__ W2,
    const float* __restrict__ b2, float* __restrict__ out, int n_nodes)
{
    const int wave = threadIdx.x >> 6;
    const int lane = threadIdx.x & 63;
    const int n = blockIdx.x * 4 + wave;
    if (n >= n_nodes) return;
    float h0 = hc[(size_t)n * 128 + lane];
    float h1 = hc[(size_t)n * 128 + 64 + lane];
    float p0 = h0 * W2[lane * 2 + 0] + h1 * W2[(64 + lane) * 2 + 0];
    float p1 = h0 * W2[lane * 2 + 1] + h1 * W2[(64 + lane) * 2 + 1];
    #pragma unroll
    for (int off = 1; off < 64; off <<= 1) {
        p0 += __shfl_xor(p0, off);
        p1 += __shfl_xor(p1, off);
    }
    if (lane == 0) {
        out[(size_t)n * 2 + 0] = p0 + b2[0];
        out[(size_t)n * 2 + 1] = p1 + b2[1];
    }
}

// ---------------------------------------------------------------------------
extern "C" void kernel_launch(void* const* d_in, const int* in_sizes, int n_in,
                              void* d_out, int out_size, void* d_ws, size_t ws_size,
                              hipStream_t stream)
{
    const float* x        = (const float*)d_in[0];
    const int*   tut_ei   = (const int*)d_in[1];
    const int*   tdt_ei   = (const int*)d_in[2];
    const float* proj_W   = (const float*)d_in[3];
    const float* proj_b   = (const float*)d_in[4];
    const float* tut_W    = (const float*)d_in[5];
    const float* tut_asrc = (const float*)d_in[6];
    const float* tut_adst = (const float*)d_in[7];
    const float* tut_bias = (const float*)d_in[8];
    const float* tdt_W    = (const float*)d_in[9];
    const float* tdt_asrc = (const float*)d_in[10];
    const float* tdt_adst = (const float*)d_in[11];
    const float* tdt_bias = (const float*)d_in[12];
    const float* sem_att  = (const float*)d_in[13];
    const float* cls_W1   = (const float*)d_in[14];
    const float* cls_b1   = (const float*)d_in[15];
    const float* cls_W2   = (const float*)d_in[16];
    const float* cls_b2   = (const float*)d_in[17];

    const int IN_CH = 128;
    const int N = in_sizes[0] / IN_CH;     // 50000
    const int E = in_sizes[1] / 2;         // 800000

    // ------------------------ workspace layout ------------------------
    char* base = (char*)d_ws;
    size_t off = 0;
    auto alloc = [&](size_t bytes) -> void* {
        void* p = base + off;
        off = (off + bytes + 255) & ~(size_t)255;
        return p;
    };
    float* h0    = (float*)alloc((size_t)N * HID * sizeof(float));
    float* bufA  = (float*)alloc((size_t)N * HID * sizeof(float));
    float* bufB  = (float*)alloc((size_t)N * HID * sizeof(float));
    float* bufT  = (float*)alloc((size_t)N * HID * sizeof(float));
    float* a_src = (float*)alloc((size_t)N * HEADS * sizeof(float));
    float* a_dst = (float*)alloc((size_t)N * HEADS * sizeof(float));
    int* rp_tut  = (int*)alloc((size_t)(N + 1) * sizeof(int));
    int* adj_tut = (int*)alloc((size_t)(E + N) * sizeof(int));
    int* rp_tdt  = (int*)alloc((size_t)(N + 1) * sizeof(int));
    int* adj_tdt = (int*)alloc((size_t)(E + N) * sizeof(int));
    int* cursor  = (int*)alloc((size_t)N * sizeof(int));    // also used as deg
    int* bsums   = (int*)alloc(256 * sizeof(int));
    (void)ws_size; (void)n_in; (void)out_size;

    const int nodeBlocks = (N + 3) / 4;
    const int scanBlocks = (N + 1023) / 1024;   // 49

    // ---------------------------- CSR build ---------------------------
    auto build_csr = [&](const int* ei, int* row_ptr, int* adj) {
        hipMemsetAsync(cursor, 0, (size_t)N * sizeof(int), stream);
        deg_count_kernel<<<1024, 256, 0, stream>>>(ei + E, cursor, E);
        scan_block_kernel<<<scanBlocks, 256, 0, stream>>>(cursor, row_ptr, bsums, N);
        scan_sums_kernel<<<1, 64, 0, stream>>>(bsums, scanBlocks);
        scan_fixup_kernel<<<(N + 255) / 256, 256, 0, stream>>>(row_ptr, bsums, N);
        init_cursor_selfloop_kernel<<<(N + 255) / 256, 256, 0, stream>>>(row_ptr, cursor, adj, N);
        edge_scatter_kernel<<<1024, 256, 0, stream>>>(ei, ei + E, cursor, adj, E);
    };
    build_csr(tut_ei, rp_tut, adj_tut);
    build_csr(tdt_ei, rp_tdt, adj_tdt);

    // ------------------------------ proj ------------------------------
    {
        dim3 g(HID / 64, (N + 127) / 128);
        sgemm_kernel<<<g, 256, 0, stream>>>(x, proj_W, proj_b, h0, N, HID, IN_CH, 0);
    }

    // ---------------------------- GAT layers --------------------------
    auto run_gat = [&](const float* in, const float* W, const float* asrc_w,
                       const float* adst_w, const float* bias,
                       const int* row_ptr, const int* adj, float* outbuf) {
        dim3 g(HID / 64, (N + 127) / 128);
        sgemm_kernel<<<g, 256, 0, stream>>>(in, W, nullptr, bufA, N, HID, HID, 0);
        att_kernel<<<nodeBlocks, 256, 0, stream>>>(bufA, asrc_w, adst_w, a_src, a_dst, N);
        gat_kernel<<<nodeBlocks, 256, 0, stream>>>(bufA, a_src, a_dst, row_ptr, adj, bias, outbuf, N);
    };

    const int WS = HID * HID;
    const int AS = HEADS * HEAD_DIM;

    run_gat(h0,   tut_W,      tut_asrc,      tut_adst,      tut_bias,       rp_tut, adj_tut, bufB);
    run_gat(bufB, tut_W + WS, tut_asrc + AS, tut_adst + AS, tut_bias + HID, rp_tut, adj_tut, bufT);
    run_gat(h0,   tdt_W,      tdt_asrc,      tdt_adst,      tdt_bias,       rp_tdt, adj_tdt, bufB);
    run_gat(bufB, tdt_W + WS, tdt_asrc + AS, tdt_adst + AS, tdt_bias + HID, rp_tdt, adj_tdt, bufB);

    // ------------------------- combine + classifier -------------------
    {
        int count4 = N * HID / 4;
        combine_kernel<<<2048, 256, 0, stream>>>(bufT, bufB, sem_att, bufA, count4);
        dim3 g(128 / 64, (N + 127) / 128);
        sgemm_kernel<<<g, 256, 0, stream>>>(bufA, cls_W1, cls_b1, h0, N, 128, HID, 1);
        cls2_kernel<<<nodeBlocks, 256, 0, stream>>>(h0, cls_W2, cls_b2, (float*)d_out, N);
    }
}

// Round 3
// 1313.485 us; speedup vs baseline: 1.3258x; 1.0038x over previous
//
#include <hip/hip_runtime.h>
#include <cstddef>
#include <cstdint>

// ---------------------------------------------------------------------------
// SimpleHAN on MI355X — round 2:
//   - gat phase-2 gather unrolled x4 (memory-level parallelism; was latency-
//     bound at 45% HBM BW)
//   - SGEMM 128x128 tile, 8x8 acc in 2x2 quadrants (conflict-free LDS reads,
//     2048cy between barriers)
//   - semantic combine fused into classifier GEMM A-staging
// ---------------------------------------------------------------------------

#define HID        256
#define HEADS      8
#define HEAD_DIM   32
#define NEG_SLOPE  0.2f

// ---------------------------- SGEMM (128x128 tile) -------------------------
// C[M,N] = A[M,K] @ B[K,N] (+bias)(+relu). K%16==0, N%128==0.
// If A2 != nullptr: effective A = w0*A + w1*A2 with (w0,w1)=softmax(sem[0:2]).
// 256 threads; per-thread 8x8 acc as 2x2 quadrants of 4x4; BK=16.
__global__ __launch_bounds__(256) void sgemm_kernel(
    const float* __restrict__ A, const float* __restrict__ A2,
    const float* __restrict__ sem,
    const float* __restrict__ B,
    const float* __restrict__ bias, float* __restrict__ C,
    int M, int N, int K, int act)
{
    __shared__ float As[16][128];  // [k][m] 8 KB
    __shared__ float Bs[16][128];  // [k][n] 8 KB

    const int tid = threadIdx.x;
    const int tx = tid & 15;       // col quadrant offset (4 cols, x2 quadrants)
    const int ty = tid >> 4;       // row quadrant offset (4 rows, x2 quadrants)
    const int m0 = blockIdx.y * 128;
    const int n0 = blockIdx.x * 128;

    float w0 = 1.f, w1 = 0.f;
    if (A2) {
        float e0 = __expf(sem[0]);
        float e1 = __expf(sem[1]);
        w0 = e0 / (e0 + e1);
        w1 = e1 / (e0 + e1);
    }

    // A loader: row lm = tid>>1 (0..127), k offset lk = (tid&1)*8
    const int lm = tid >> 1;
    const int lk = (tid & 1) * 8;
    // B loader: row lr = tid>>4 (0..15), col lc8 = (tid&15)*8
    const int lr = tid >> 4;
    const int lc8 = (tid & 15) * 8;

    float4 acc[2][2][4];
    #pragma unroll
    for (int rh = 0; rh < 2; ++rh)
        #pragma unroll
        for (int ch = 0; ch < 2; ++ch)
            #pragma unroll
            for (int i = 0; i < 4; ++i)
                acc[rh][ch][i] = make_float4(0.f, 0.f, 0.f, 0.f);

    for (int k0 = 0; k0 < K; k0 += 16) {
        float4 a0 = make_float4(0.f, 0.f, 0.f, 0.f);
        float4 a1 = make_float4(0.f, 0.f, 0.f, 0.f);
        if (m0 + lm < M) {
            const float* ap = &A[(size_t)(m0 + lm) * K + k0 + lk];
            a0 = *reinterpret_cast<const float4*>(ap);
            a1 = *reinterpret_cast<const float4*>(ap + 4);
            if (A2) {
                const float* ap2 = &A2[(size_t)(m0 + lm) * K + k0 + lk];
                float4 b0 = *reinterpret_cast<const float4*>(ap2);
                float4 b1 = *reinterpret_cast<const float4*>(ap2 + 4);
                a0.x = w0 * a0.x + w1 * b0.x; a0.y = w0 * a0.y + w1 * b0.y;
                a0.z = w0 * a0.z + w1 * b0.z; a0.w = w0 * a0.w + w1 * b0.w;
                a1.x = w0 * a1.x + w1 * b1.x; a1.y = w0 * a1.y + w1 * b1.y;
                a1.z = w0 * a1.z + w1 * b1.z; a1.w = w0 * a1.w + w1 * b1.w;
            }
        }
        As[lk + 0][lm] = a0.x; As[lk + 1][lm] = a0.y;
        As[lk + 2][lm] = a0.z; As[lk + 3][lm] = a0.w;
        As[lk + 4][lm] = a1.x; As[lk + 5][lm] = a1.y;
        As[lk + 6][lm] = a1.z; As[lk + 7][lm] = a1.w;

        {
            const float* bp = &B[(size_t)(k0 + lr) * N + n0 + lc8];
            float4 b0 = *reinterpret_cast<const float4*>(bp);
            float4 b1 = *reinterpret_cast<const float4*>(bp + 4);
            *reinterpret_cast<float4*>(&Bs[lr][lc8]) = b0;
            *reinterpret_cast<float4*>(&Bs[lr][lc8 + 4]) = b1;
        }
        __syncthreads();

        #pragma unroll
        for (int k = 0; k < 16; ++k) {
            float4 av[2], bv[2];
            av[0] = *reinterpret_cast<const float4*>(&As[k][ty * 4]);
            av[1] = *reinterpret_cast<const float4*>(&As[k][64 + ty * 4]);
            bv[0] = *reinterpret_cast<const float4*>(&Bs[k][tx * 4]);
            bv[1] = *reinterpret_cast<const float4*>(&Bs[k][64 + tx * 4]);
            #pragma unroll
            for (int rh = 0; rh < 2; ++rh) {
                float ar[4] = {av[rh].x, av[rh].y, av[rh].z, av[rh].w};
                #pragma unroll
                for (int i = 0; i < 4; ++i) {
                    #pragma unroll
                    for (int ch = 0; ch < 2; ++ch) {
                        acc[rh][ch][i].x += ar[i] * bv[ch].x;
                        acc[rh][ch][i].y += ar[i] * bv[ch].y;
                        acc[rh][ch][i].z += ar[i] * bv[ch].z;
                        acc[rh][ch][i].w += ar[i] * bv[ch].w;
                    }
                }
            }
        }
        __syncthreads();
    }

    float4 bvec[2] = {make_float4(0.f, 0.f, 0.f, 0.f), make_float4(0.f, 0.f, 0.f, 0.f)};
    if (bias) {
        bvec[0] = *reinterpret_cast<const float4*>(&bias[n0 + tx * 4]);
        bvec[1] = *reinterpret_cast<const float4*>(&bias[n0 + 64 + tx * 4]);
    }
    #pragma unroll
    for (int rh = 0; rh < 2; ++rh) {
        #pragma unroll
        for (int i = 0; i < 4; ++i) {
            int row = m0 + rh * 64 + ty * 4 + i;
            if (row < M) {
                #pragma unroll
                for (int ch = 0; ch < 2; ++ch) {
                    float4 o;
                    o.x = acc[rh][ch][i].x + bvec[ch].x;
                    o.y = acc[rh][ch][i].y + bvec[ch].y;
                    o.z = acc[rh][ch][i].z + bvec[ch].z;
                    o.w = acc[rh][ch][i].w + bvec[ch].w;
                    if (act == 1) {
                        o.x = fmaxf(o.x, 0.f); o.y = fmaxf(o.y, 0.f);
                        o.z = fmaxf(o.z, 0.f); o.w = fmaxf(o.w, 0.f);
                    }
                    *reinterpret_cast<float4*>(&C[(size_t)row * N + n0 + ch * 64 + tx * 4]) = o;
                }
            }
        }
    }
}

// ------------------------- attention dot products --------------------------
__global__ __launch_bounds__(256) void att_kernel(
    const float* __restrict__ hW,
    const float* __restrict__ att_src, const float* __restrict__ att_dst,
    float* __restrict__ a_src, float* __restrict__ a_dst, int n_nodes)
{
    const int wave = threadIdx.x >> 6;
    const int lane = threadIdx.x & 63;
    const int n = blockIdx.x * 4 + wave;
    if (n >= n_nodes) return;

    float4 hv = *reinterpret_cast<const float4*>(&hW[(size_t)n * HID + lane * 4]);
    float4 s4 = *reinterpret_cast<const float4*>(&att_src[lane * 4]);
    float4 d4 = *reinterpret_cast<const float4*>(&att_dst[lane * 4]);
    float ps = hv.x * s4.x + hv.y * s4.y + hv.z * s4.z + hv.w * s4.w;
    float pd = hv.x * d4.x + hv.y * d4.y + hv.z * d4.z + hv.w * d4.w;
    #pragma unroll
    for (int off = 1; off < 8; off <<= 1) {
        ps += __shfl_xor(ps, off);
        pd += __shfl_xor(pd, off);
    }
    if ((lane & 7) == 0) {
        a_src[n * HEADS + (lane >> 3)] = ps;
        a_dst[n * HEADS + (lane >> 3)] = pd;
    }
}

// --------------------- GAT softmax + aggregation (CSR) ----------------------
__global__ __launch_bounds__(256) void gat_kernel(
    const float* __restrict__ hW,
    const float* __restrict__ a_src, const float* __restrict__ a_dst,
    const int* __restrict__ row_ptr, const int* __restrict__ adj,
    const float* __restrict__ bias, float* __restrict__ out, int n_nodes)
{
    const int wave = threadIdx.x >> 6;
    const int lane = threadIdx.x & 63;
    const int n = blockIdx.x * 4 + wave;
    if (n >= n_nodes) return;

    const int beg = row_ptr[n];
    const int end = row_ptr[n + 1];

    // phase 1: lane handles head h1 = lane&7, neighbor slot = lane>>3
    const int h1 = lane & 7;
    const float adst1 = a_dst[n * HEADS + h1];
    float m = -INFINITY, s = 0.f;
    for (int j = beg + (lane >> 3); j < end; j += 8) {
        float e = a_src[adj[j] * HEADS + h1] + adst1;
        e = (e > 0.f) ? e : NEG_SLOPE * e;
        float mn = fmaxf(m, e);
        float t = (m > -INFINITY) ? s * __expf(m - mn) : 0.f;
        s = t + __expf(e - mn);
        m = mn;
    }
    #pragma unroll
    for (int off = 8; off < 64; off <<= 1) {
        float mo = __shfl_xor(m, off);
        float so = __shfl_xor(s, off);
        float mn = fmaxf(m, mo);
        float t1 = (m  > -INFINITY) ? s  * __expf(m  - mn) : 0.f;
        float t2 = (mo > -INFINITY) ? so * __expf(mo - mn) : 0.f;
        s = t1 + t2;
        m = mn;
    }

    const int h2 = lane >> 3;
    const float mh  = __shfl(m, h2);
    const float sh  = __shfl(s, h2);
    const float inv = 1.f / (sh + 1e-16f);
    const float adst2 = a_dst[n * HEADS + h2];
    const int lane4 = lane * 4;

    float4 acc = make_float4(0.f, 0.f, 0.f, 0.f);
    int j = beg;
    // phase 2: 4 edges in flight per iteration (MLP against HBM latency)
    for (; j + 4 <= end; j += 4) {
        int s0 = adj[j + 0], s1 = adj[j + 1], s2 = adj[j + 2], s3 = adj[j + 3];
        float e0 = a_src[s0 * HEADS + h2] + adst2;
        float e1 = a_src[s1 * HEADS + h2] + adst2;
        float e2 = a_src[s2 * HEADS + h2] + adst2;
        float e3 = a_src[s3 * HEADS + h2] + adst2;
        e0 = (e0 > 0.f) ? e0 : NEG_SLOPE * e0;
        e1 = (e1 > 0.f) ? e1 : NEG_SLOPE * e1;
        e2 = (e2 > 0.f) ? e2 : NEG_SLOPE * e2;
        e3 = (e3 > 0.f) ? e3 : NEG_SLOPE * e3;
        float al0 = __expf(e0 - mh) * inv;
        float al1 = __expf(e1 - mh) * inv;
        float al2 = __expf(e2 - mh) * inv;
        float al3 = __expf(e3 - mh) * inv;
        float4 h0v = *reinterpret_cast<const float4*>(&hW[(size_t)s0 * HID + lane4]);
        float4 h1v = *reinterpret_cast<const float4*>(&hW[(size_t)s1 * HID + lane4]);
        float4 h2v = *reinterpret_cast<const float4*>(&hW[(size_t)s2 * HID + lane4]);
        float4 h3v = *reinterpret_cast<const float4*>(&hW[(size_t)s3 * HID + lane4]);
        acc.x += al0 * h0v.x; acc.y += al0 * h0v.y; acc.z += al0 * h0v.z; acc.w += al0 * h0v.w;
        acc.x += al1 * h1v.x; acc.y += al1 * h1v.y; acc.z += al1 * h1v.z; acc.w += al1 * h1v.w;
        acc.x += al2 * h2v.x; acc.y += al2 * h2v.y; acc.z += al2 * h2v.z; acc.w += al2 * h2v.w;
        acc.x += al3 * h3v.x; acc.y += al3 * h3v.y; acc.z += al3 * h3v.z; acc.w += al3 * h3v.w;
    }
    for (; j < end; ++j) {
        int src = adj[j];
        float e = a_src[src * HEADS + h2] + adst2;
        e = (e > 0.f) ? e : NEG_SLOPE * e;
        float alpha = __expf(e - mh) * inv;
        float4 hv = *reinterpret_cast<const float4*>(&hW[(size_t)src * HID + lane4]);
        acc.x += alpha * hv.x;
        acc.y += alpha * hv.y;
        acc.z += alpha * hv.z;
        acc.w += alpha * hv.w;
    }

    float4 bv = *reinterpret_cast<const float4*>(&bias[lane4]);
    float4 o;
    o.x = acc.x + bv.x; o.y = acc.y + bv.y; o.z = acc.z + bv.z; o.w = acc.w + bv.w;
    o.x = (o.x > 0.f) ? o.x : expm1f(o.x);
    o.y = (o.y > 0.f) ? o.y : expm1f(o.y);
    o.z = (o.z > 0.f) ? o.z : expm1f(o.z);
    o.w = (o.w > 0.f) ? o.w : expm1f(o.w);
    *reinterpret_cast<float4*>(&out[(size_t)n * HID + lane4]) = o;
}

// ------------------------------- CSR build ---------------------------------
__global__ void deg_count_kernel(const int* __restrict__ dst, int* __restrict__ deg, int E)
{
    for (int e = blockIdx.x * blockDim.x + threadIdx.x; e < E; e += gridDim.x * blockDim.x)
        atomicAdd(&deg[dst[e]], 1);
}

__global__ __launch_bounds__(256) void scan_block_kernel(
    const int* __restrict__ deg, int* __restrict__ row_ptr,
    int* __restrict__ blockSums, int n)
{
    __shared__ int sm[256];
    const int tid = threadIdx.x;
    const int i0 = blockIdx.x * 1024 + tid * 4;
    int v0 = (i0 + 0 < n) ? deg[i0 + 0] + 1 : 0;
    int v1 = (i0 + 1 < n) ? deg[i0 + 1] + 1 : 0;
    int v2 = (i0 + 2 < n) ? deg[i0 + 2] + 1 : 0;
    int v3 = (i0 + 3 < n) ? deg[i0 + 3] + 1 : 0;
    int s1 = v0 + v1, s2 = s1 + v2, s3 = s2 + v3;
    sm[tid] = s3;
    __syncthreads();
    #pragma unroll
    for (int off = 1; off < 256; off <<= 1) {
        int t = (tid >= off) ? sm[tid - off] : 0;
        __syncthreads();
        sm[tid] += t;
        __syncthreads();
    }
    int prev = (tid > 0) ? sm[tid - 1] : 0;
    if (tid == 255) blockSums[blockIdx.x] = sm[255];
    if (i0 + 0 < n) row_ptr[i0 + 1] = prev + v0;
    if (i0 + 1 < n) row_ptr[i0 + 2] = prev + s1;
    if (i0 + 2 < n) row_ptr[i0 + 3] = prev + s2;
    if (i0 + 3 < n) row_ptr[i0 + 4] = prev + s3;
}

__global__ void scan_sums_kernel(int* __restrict__ blockSums, int nb)
{
    const int lane = threadIdx.x;
    int v = (lane < nb) ? blockSums[lane] : 0;
    #pragma unroll
    for (int off = 1; off < 64; off <<= 1) {
        int t = __shfl_up(v, off);
        if (lane >= off) v += t;
    }
    if (lane < nb) blockSums[lane] = v;
}

__global__ __launch_bounds__(256) void scan_fixup_kernel(
    int* __restrict__ row_ptr, const int* __restrict__ blockSums, int n)
{
    int i = blockIdx.x * blockDim.x + threadIdx.x;
    if (i == 0) row_ptr[0] = 0;
    if (i < n) {
        int b = i >> 10;
        if (b > 0) row_ptr[i + 1] += blockSums[b - 1];
    }
}

__global__ void init_cursor_selfloop_kernel(
    const int* __restrict__ row_ptr, int* __restrict__ cursor,
    int* __restrict__ adj, int n)
{
    int i = blockIdx.x * blockDim.x + threadIdx.x;
    if (i < n) {
        int p = row_ptr[i];
        adj[p] = i;
        cursor[i] = p + 1;
    }
}

__global__ void edge_scatter_kernel(
    const int* __restrict__ src, const int* __restrict__ dst,
    int* __restrict__ cursor, int* __restrict__ adj, int E)
{
    for (int e = blockIdx.x * blockDim.x + threadIdx.x; e < E; e += gridDim.x * blockDim.x) {
        int pos = atomicAdd(&cursor[dst[e]], 1);
        adj[pos] = src[e];
    }
}

// ------------------------------- classifier --------------------------------
__global__ __launch_bounds__(256) void cls2_kernel(
    const float* __restrict__ hc, const float* __restrict__ W2,
    const float* __restrict__ b2, float* __restrict__ out, int n_nodes)
{
    const int wave = threadIdx.x >> 6;
    const int lane = threadIdx.x & 63;
    const int n = blockIdx.x * 4 + wave;
    if (n >= n_nodes) return;
    float h0 = hc[(size_t)n * 128 + lane];
    float h1 = hc[(size_t)n * 128 + 64 + lane];
    float p0 = h0 * W2[lane * 2 + 0] + h1 * W2[(64 + lane) * 2 + 0];
    float p1 = h0 * W2[lane * 2 + 1] + h1 * W2[(64 + lane) * 2 + 1];
    #pragma unroll
    for (int off = 1; off < 64; off <<= 1) {
        p0 += __shfl_xor(p0, off);
        p1 += __shfl_xor(p1, off);
    }
    if (lane == 0) {
        out[(size_t)n * 2 + 0] = p0 + b2[0];
        out[(size_t)n * 2 + 1] = p1 + b2[1];
    }
}

// ---------------------------------------------------------------------------
extern "C" void kernel_launch(void* const* d_in, const int* in_sizes, int n_in,
                              void* d_out, int out_size, void* d_ws, size_t ws_size,
                              hipStream_t stream)
{
    const float* x        = (const float*)d_in[0];
    const int*   tut_ei   = (const int*)d_in[1];
    const int*   tdt_ei   = (const int*)d_in[2];
    const float* proj_W   = (const float*)d_in[3];
    const float* proj_b   = (const float*)d_in[4];
    const float* tut_W    = (const float*)d_in[5];
    const float* tut_asrc = (const float*)d_in[6];
    const float* tut_adst = (const float*)d_in[7];
    const float* tut_bias = (const float*)d_in[8];
    const float* tdt_W    = (const float*)d_in[9];
    const float* tdt_asrc = (const float*)d_in[10];
    const float* tdt_adst = (const float*)d_in[11];
    const float* tdt_bias = (const float*)d_in[12];
    const float* sem_att  = (const float*)d_in[13];
    const float* cls_W1   = (const float*)d_in[14];
    const float* cls_b1   = (const float*)d_in[15];
    const float* cls_W2   = (const float*)d_in[16];
    const float* cls_b2   = (const float*)d_in[17];

    const int IN_CH = 128;
    const int N = in_sizes[0] / IN_CH;     // 50000
    const int E = in_sizes[1] / 2;         // 800000

    // ------------------------ workspace layout ------------------------
    char* base = (char*)d_ws;
    size_t off = 0;
    auto alloc = [&](size_t bytes) -> void* {
        void* p = base + off;
        off = (off + bytes + 255) & ~(size_t)255;
        return p;
    };
    float* h0    = (float*)alloc((size_t)N * HID * sizeof(float));
    float* bufA  = (float*)alloc((size_t)N * HID * sizeof(float));
    float* bufB  = (float*)alloc((size_t)N * HID * sizeof(float));
    float* bufT  = (float*)alloc((size_t)N * HID * sizeof(float));
    float* a_src = (float*)alloc((size_t)N * HEADS * sizeof(float));
    float* a_dst = (float*)alloc((size_t)N * HEADS * sizeof(float));
    int* rp_tut  = (int*)alloc((size_t)(N + 1) * sizeof(int));
    int* adj_tut = (int*)alloc((size_t)(E + N) * sizeof(int));
    int* rp_tdt  = (int*)alloc((size_t)(N + 1) * sizeof(int));
    int* adj_tdt = (int*)alloc((size_t)(E + N) * sizeof(int));
    int* cursor  = (int*)alloc((size_t)N * sizeof(int));
    int* bsums   = (int*)alloc(256 * sizeof(int));
    (void)ws_size; (void)n_in; (void)out_size;

    const int nodeBlocks = (N + 3) / 4;
    const int scanBlocks = (N + 1023) / 1024;

    // ---------------------------- CSR build ---------------------------
    auto build_csr = [&](const int* ei, int* row_ptr, int* adj) {
        hipMemsetAsync(cursor, 0, (size_t)N * sizeof(int), stream);
        deg_count_kernel<<<1024, 256, 0, stream>>>(ei + E, cursor, E);
        scan_block_kernel<<<scanBlocks, 256, 0, stream>>>(cursor, row_ptr, bsums, N);
        scan_sums_kernel<<<1, 64, 0, stream>>>(bsums, scanBlocks);
        scan_fixup_kernel<<<(N + 255) / 256, 256, 0, stream>>>(row_ptr, bsums, N);
        init_cursor_selfloop_kernel<<<(N + 255) / 256, 256, 0, stream>>>(row_ptr, cursor, adj, N);
        edge_scatter_kernel<<<1024, 256, 0, stream>>>(ei, ei + E, cursor, adj, E);
    };
    build_csr(tut_ei, rp_tut, adj_tut);
    build_csr(tdt_ei, rp_tdt, adj_tdt);

    // ------------------------------ proj ------------------------------
    {
        dim3 g(HID / 128, (N + 127) / 128);
        sgemm_kernel<<<g, 256, 0, stream>>>(x, nullptr, nullptr, proj_W, proj_b, h0,
                                            N, HID, IN_CH, 0);
    }

    // ---------------------------- GAT layers --------------------------
    auto run_gat = [&](const float* in, const float* W, const float* asrc_w,
                       const float* adst_w, const float* bias,
                       const int* row_ptr, const int* adj, float* outbuf) {
        dim3 g(HID / 128, (N + 127) / 128);
        sgemm_kernel<<<g, 256, 0, stream>>>(in, nullptr, nullptr, W, nullptr, bufA,
                                            N, HID, HID, 0);
        att_kernel<<<nodeBlocks, 256, 0, stream>>>(bufA, asrc_w, adst_w, a_src, a_dst, N);
        gat_kernel<<<nodeBlocks, 256, 0, stream>>>(bufA, a_src, a_dst, row_ptr, adj, bias, outbuf, N);
    };

    const int WS = HID * HID;
    const int AS = HEADS * HEAD_DIM;

    run_gat(h0,   tut_W,      tut_asrc,      tut_adst,      tut_bias,       rp_tut, adj_tut, bufB);
    run_gat(bufB, tut_W + WS, tut_asrc + AS, tut_adst + AS, tut_bias + HID, rp_tut, adj_tut, bufT);
    run_gat(h0,   tdt_W,      tdt_asrc,      tdt_adst,      tdt_bias,       rp_tdt, adj_tdt, bufB);
    run_gat(bufB, tdt_W + WS, tdt_asrc + AS, tdt_adst + AS, tdt_bias + HID, rp_tdt, adj_tdt, bufB);

    // ---------------- classifier (combine fused into GEMM A) ----------
    {
        dim3 g(128 / 128, (N + 127) / 128);
        sgemm_kernel<<<g, 256, 0, stream>>>(bufT, bufB, sem_att, cls_W1, cls_b1, h0,
                                            N, 128, HID, 1);
        cls2_kernel<<<nodeBlocks, 256, 0, stream>>>(h0, cls_W2, cls_b2, (float*)d_out, N);
    }
}

// Round 4
// 909.668 us; speedup vs baseline: 1.9144x; 1.4439x over previous
//
#include <hip/hip_runtime.h>
#include <hip/hip_fp16.h>
#include <cstddef>
#include <cstdint>

// ---------------------------------------------------------------------------
// SimpleHAN on MI355X — round 3:
//   - GEMMs moved to MFMA bf16x3 split (A,B split into bf16 hi/lo; 3 products
//     => ~fp32 accuracy at matrix-core rate). global_load_lds staging.
//   - value gather (gat phase 2) + att dots read hW in fp16 (half traffic).
//   - activations carried as bf16 hi/lo pairs between layers.
// ---------------------------------------------------------------------------

#define HID        256
#define HEADS      8
#define NEG_SLOPE  0.2f

typedef __attribute__((ext_vector_type(8))) short short8v;
typedef __attribute__((ext_vector_type(4))) float float4v;

static __device__ __forceinline__ unsigned short f32_to_bf16(float v) {
    union { float f; unsigned u; } c; c.f = v;
    unsigned r = c.u + 0x7FFFu + ((c.u >> 16) & 1u);
    return (unsigned short)(r >> 16);
}
static __device__ __forceinline__ float bf16_to_f32(unsigned short b) {
    union { unsigned u; float f; } c; c.u = ((unsigned)b) << 16;
    return c.f;
}
static __device__ __forceinline__ void split_bf16(float v, unsigned short& hi, unsigned short& lo) {
    hi = f32_to_bf16(v);
    lo = f32_to_bf16(v - bf16_to_f32(hi));
}
static __device__ __forceinline__ void gload_lds16(const void* g, void* l) {
    __builtin_amdgcn_global_load_lds((const __attribute__((address_space(1))) void*)g,
                                     (__attribute__((address_space(3))) void*)l, 16, 0, 0);
}

// ------------------------- MFMA GEMM (bf16x3 split) ------------------------
// C[M,N] = (Ahi+Alo)[M,K] @ (Bthi+Btlo)[N,K]^T  (+bias)
// Bt is TRANSPOSED weights [N][K] so K is contiguous for both operands.
// BM=128, BN=128, BK=32, 256 threads = 4 waves (2x2), per-wave 64x64 tile.
// LDS: 4 arrays (Ahi,Alo,Bhi,Blo) x 4 k-chunks x 128 rows x 16B.
// MODE 0: write split bf16 hi/lo (+bias). MODE 1: write fp16. MODE 2: fp32+bias+relu.
template<int MODE>
__global__ __launch_bounds__(256) void mfma_gemm_kernel(
    const unsigned short* __restrict__ Ahi, const unsigned short* __restrict__ Alo,
    const unsigned short* __restrict__ Bthi, const unsigned short* __restrict__ Btlo,
    const float* __restrict__ bias,
    unsigned short* __restrict__ Chi, unsigned short* __restrict__ Clo,
    __half* __restrict__ Cf16, float* __restrict__ Cf32,
    int M, int N, int K)
{
    __shared__ __align__(16) short lds[4 * 4096];  // 32 KB

    const int tid  = threadIdx.x;
    const int lane = tid & 63;
    const int w    = tid >> 6;        // wave id 0..3
    const int wr   = w >> 1;          // wave row (0..1)
    const int wc   = w & 1;           // wave col (0..1)
    const int m0   = blockIdx.y * 128;
    const int n0   = blockIdx.x * 128;

    // staging role: wave w stages array w of {Ahi, Alo, Bthi, Btlo}
    const unsigned short* sbase = (w == 0) ? Ahi : (w == 1) ? Alo : (w == 2) ? Bthi : Btlo;
    const int rowbase = (w < 2) ? m0 : n0;
    const int rowlim  = ((w < 2) ? M : N) - 1;

    float4v acc[4][4];
    #pragma unroll
    for (int i = 0; i < 4; ++i)
        #pragma unroll
        for (int j = 0; j < 4; ++j)
            acc[i][j] = (float4v){0.f, 0.f, 0.f, 0.f};

    const int kcl = lane >> 4;    // k-chunk from lane (0..3)
    const int rl  = lane & 15;    // row-in-fragment from lane

    for (int k0 = 0; k0 < K; k0 += 32) {
        // ---- stage: 8 x global_load_lds(16B) per wave ----
        #pragma unroll
        for (int rh = 0; rh < 2; ++rh) {
            int row = rowbase + rh * 64 + lane;
            row = row > rowlim ? rowlim : row;
            const unsigned short* src = sbase + (size_t)row * K + k0;
            #pragma unroll
            for (int kc = 0; kc < 4; ++kc) {
                short* dst = &lds[w * 4096 + kc * 1024 + rh * 512];  // wave-uniform
                gload_lds16(src + kc * 8, dst);
            }
        }
        __syncthreads();

        // ---- fragments: lane l -> row (l&15), k = (l>>4)*8 + j ----
        short8v ahi[4], alo[4], bhi[4], blo[4];
        #pragma unroll
        for (int i = 0; i < 4; ++i) {
            int am = wr * 64 + i * 16 + rl;
            int bn = wc * 64 + i * 16 + rl;
            ahi[i] = *(const short8v*)&lds[0 * 4096 + kcl * 1024 + am * 8];
            alo[i] = *(const short8v*)&lds[1 * 4096 + kcl * 1024 + am * 8];
            bhi[i] = *(const short8v*)&lds[2 * 4096 + kcl * 1024 + bn * 8];
            blo[i] = *(const short8v*)&lds[3 * 4096 + kcl * 1024 + bn * 8];
        }
        #pragma unroll
        for (int i = 0; i < 4; ++i)
            #pragma unroll
            for (int j = 0; j < 4; ++j) {
                acc[i][j] = __builtin_amdgcn_mfma_f32_16x16x32_bf16(ahi[i], bhi[j], acc[i][j], 0, 0, 0);
                acc[i][j] = __builtin_amdgcn_mfma_f32_16x16x32_bf16(ahi[i], blo[j], acc[i][j], 0, 0, 0);
                acc[i][j] = __builtin_amdgcn_mfma_f32_16x16x32_bf16(alo[i], bhi[j], acc[i][j], 0, 0, 0);
            }
        __syncthreads();
    }

    // ---- epilogue: C/D map col=lane&15, row=(lane>>4)*4+r (m89-verified) ----
    const int cr = (lane >> 4) * 4;
    #pragma unroll
    for (int i = 0; i < 4; ++i) {
        #pragma unroll
        for (int r = 0; r < 4; ++r) {
            int row = m0 + wr * 64 + i * 16 + cr + r;
            if (row >= M) continue;
            #pragma unroll
            for (int j = 0; j < 4; ++j) {
                int col = n0 + wc * 64 + j * 16 + rl;
                float v = acc[i][j][r];
                if (bias) v += bias[col];
                if (MODE == 0) {
                    unsigned short h, l;
                    split_bf16(v, h, l);
                    Chi[(size_t)row * N + col] = h;
                    Clo[(size_t)row * N + col] = l;
                } else if (MODE == 1) {
                    Cf16[(size_t)row * N + col] = __float2half(v);
                } else {
                    Cf32[(size_t)row * N + col] = fmaxf(v, 0.f);
                }
            }
        }
    }
}

// --------------------------- prep / split kernels --------------------------
// fp32 [count4*4] -> bf16 hi/lo, 4 elems/thread
__global__ void split4_kernel(const float* __restrict__ X,
                              unsigned short* __restrict__ hi,
                              unsigned short* __restrict__ lo, int count4)
{
    int i = blockIdx.x * blockDim.x + threadIdx.x;
    if (i >= count4) return;
    float4 v = reinterpret_cast<const float4*>(X)[i];
    ushort4 h, l;
    split_bf16(v.x, h.x, l.x);
    split_bf16(v.y, h.y, l.y);
    split_bf16(v.z, h.z, l.z);
    split_bf16(v.w, h.w, l.w);
    reinterpret_cast<ushort4*>(hi)[i] = h;
    reinterpret_cast<ushort4*>(lo)[i] = l;
}

// W fp32 [K,N] -> Wt hi/lo bf16 [N,K]
__global__ void transpose_split_kernel(const float* __restrict__ W,
                                       unsigned short* __restrict__ thi,
                                       unsigned short* __restrict__ tlo,
                                       int K, int N)
{
    int idx = blockIdx.x * blockDim.x + threadIdx.x;
    if (idx >= K * N) return;
    int k = idx / N, n = idx - k * N;
    unsigned short h, l;
    split_bf16(W[idx], h, l);
    thi[(size_t)n * K + k] = h;
    tlo[(size_t)n * K + k] = l;
}

// z = w0*(Thi+Tlo) + w1*(Dhi+Dlo) -> split bf16, 4 elems/thread
__global__ void combine_split_kernel(
    const unsigned short* __restrict__ Thi, const unsigned short* __restrict__ Tlo,
    const unsigned short* __restrict__ Dhi, const unsigned short* __restrict__ Dlo,
    const float* __restrict__ sem,
    unsigned short* __restrict__ Zhi, unsigned short* __restrict__ Zlo, int count4)
{
    int i = blockIdx.x * blockDim.x + threadIdx.x;
    if (i >= count4) return;
    float e0 = __expf(sem[0]);
    float e1 = __expf(sem[1]);
    float w0 = e0 / (e0 + e1);
    float w1 = e1 / (e0 + e1);
    ushort4 th = reinterpret_cast<const ushort4*>(Thi)[i];
    ushort4 tl = reinterpret_cast<const ushort4*>(Tlo)[i];
    ushort4 dh = reinterpret_cast<const ushort4*>(Dhi)[i];
    ushort4 dl = reinterpret_cast<const ushort4*>(Dlo)[i];
    ushort4 zh, zl;
    float z;
    z = w0 * (bf16_to_f32(th.x) + bf16_to_f32(tl.x)) + w1 * (bf16_to_f32(dh.x) + bf16_to_f32(dl.x));
    split_bf16(z, zh.x, zl.x);
    z = w0 * (bf16_to_f32(th.y) + bf16_to_f32(tl.y)) + w1 * (bf16_to_f32(dh.y) + bf16_to_f32(dl.y));
    split_bf16(z, zh.y, zl.y);
    z = w0 * (bf16_to_f32(th.z) + bf16_to_f32(tl.z)) + w1 * (bf16_to_f32(dh.z) + bf16_to_f32(dl.z));
    split_bf16(z, zh.z, zl.z);
    z = w0 * (bf16_to_f32(th.w) + bf16_to_f32(tl.w)) + w1 * (bf16_to_f32(dh.w) + bf16_to_f32(dl.w));
    split_bf16(z, zh.w, zl.w);
    reinterpret_cast<ushort4*>(Zhi)[i] = zh;
    reinterpret_cast<ushort4*>(Zlo)[i] = zl;
}

// ------------------------- attention dot products --------------------------
__global__ __launch_bounds__(256) void att_kernel(
    const __half* __restrict__ hW,
    const float* __restrict__ att_src, const float* __restrict__ att_dst,
    float* __restrict__ a_src, float* __restrict__ a_dst, int n_nodes)
{
    const int wave = threadIdx.x >> 6;
    const int lane = threadIdx.x & 63;
    const int n = blockIdx.x * 4 + wave;
    if (n >= n_nodes) return;

    const __half2* hp = reinterpret_cast<const __half2*>(&hW[(size_t)n * HID + lane * 4]);
    __half2 h01 = hp[0], h23 = hp[1];
    float hx = __low2float(h01), hy = __high2float(h01);
    float hz = __low2float(h23), hw = __high2float(h23);
    float4 s4 = *reinterpret_cast<const float4*>(&att_src[lane * 4]);
    float4 d4 = *reinterpret_cast<const float4*>(&att_dst[lane * 4]);
    float ps = hx * s4.x + hy * s4.y + hz * s4.z + hw * s4.w;
    float pd = hx * d4.x + hy * d4.y + hz * d4.z + hw * d4.w;
    #pragma unroll
    for (int off = 1; off < 8; off <<= 1) {
        ps += __shfl_xor(ps, off);
        pd += __shfl_xor(pd, off);
    }
    if ((lane & 7) == 0) {
        a_src[n * HEADS + (lane >> 3)] = ps;
        a_dst[n * HEADS + (lane >> 3)] = pd;
    }
}

// --------------------- GAT softmax + aggregation (CSR) ----------------------
// hW in fp16; output written as split bf16 hi/lo (bias+ELU applied).
__global__ __launch_bounds__(256) void gat_kernel(
    const __half* __restrict__ hW,
    const float* __restrict__ a_src, const float* __restrict__ a_dst,
    const int* __restrict__ row_ptr, const int* __restrict__ adj,
    const float* __restrict__ bias,
    unsigned short* __restrict__ outhi, unsigned short* __restrict__ outlo,
    int n_nodes)
{
    const int wave = threadIdx.x >> 6;
    const int lane = threadIdx.x & 63;
    const int n = blockIdx.x * 4 + wave;
    if (n >= n_nodes) return;

    const int beg = row_ptr[n];
    const int end = row_ptr[n + 1];

    // phase 1: lane = head (lane&7) x neighbor slot (lane>>3)
    const int h1 = lane & 7;
    const float adst1 = a_dst[n * HEADS + h1];
    float m = -INFINITY, s = 0.f;
    for (int j = beg + (lane >> 3); j < end; j += 8) {
        float e = a_src[adj[j] * HEADS + h1] + adst1;
        e = (e > 0.f) ? e : NEG_SLOPE * e;
        float mn = fmaxf(m, e);
        float t = (m > -INFINITY) ? s * __expf(m - mn) : 0.f;
        s = t + __expf(e - mn);
        m = mn;
    }
    #pragma unroll
    for (int off = 8; off < 64; off <<= 1) {
        float mo = __shfl_xor(m, off);
        float so = __shfl_xor(s, off);
        float mn = fmaxf(m, mo);
        float t1 = (m  > -INFINITY) ? s  * __expf(m  - mn) : 0.f;
        float t2 = (mo > -INFINITY) ? so * __expf(mo - mn) : 0.f;
        s = t1 + t2;
        m = mn;
    }

    const int h2 = lane >> 3;
    const float mh  = __shfl(m, h2);
    const float sh  = __shfl(s, h2);
    const float inv = 1.f / (sh + 1e-16f);
    const float adst2 = a_dst[n * HEADS + h2];
    const int lane4 = lane * 4;

    float4 acc = make_float4(0.f, 0.f, 0.f, 0.f);
    int j = beg;
    for (; j + 4 <= end; j += 4) {
        int s0 = adj[j + 0], s1 = adj[j + 1], s2 = adj[j + 2], s3 = adj[j + 3];
        float e0 = a_src[s0 * HEADS + h2] + adst2;
        float e1 = a_src[s1 * HEADS + h2] + adst2;
        float e2 = a_src[s2 * HEADS + h2] + adst2;
        float e3 = a_src[s3 * HEADS + h2] + adst2;
        e0 = (e0 > 0.f) ? e0 : NEG_SLOPE * e0;
        e1 = (e1 > 0.f) ? e1 : NEG_SLOPE * e1;
        e2 = (e2 > 0.f) ? e2 : NEG_SLOPE * e2;
        e3 = (e3 > 0.f) ? e3 : NEG_SLOPE * e3;
        float al0 = __expf(e0 - mh) * inv;
        float al1 = __expf(e1 - mh) * inv;
        float al2 = __expf(e2 - mh) * inv;
        float al3 = __expf(e3 - mh) * inv;
        const __half2* p0 = reinterpret_cast<const __half2*>(&hW[(size_t)s0 * HID + lane4]);
        const __half2* p1 = reinterpret_cast<const __half2*>(&hW[(size_t)s1 * HID + lane4]);
        const __half2* p2 = reinterpret_cast<const __half2*>(&hW[(size_t)s2 * HID + lane4]);
        const __half2* p3 = reinterpret_cast<const __half2*>(&hW[(size_t)s3 * HID + lane4]);
        __half2 a01 = p0[0], a23 = p0[1];
        __half2 b01 = p1[0], b23 = p1[1];
        __half2 c01 = p2[0], c23 = p2[1];
        __half2 d01 = p3[0], d23 = p3[1];
        acc.x += al0 * __low2float(a01); acc.y += al0 * __high2float(a01);
        acc.z += al0 * __low2float(a23); acc.w += al0 * __high2float(a23);
        acc.x += al1 * __low2float(b01); acc.y += al1 * __high2float(b01);
        acc.z += al1 * __low2float(b23); acc.w += al1 * __high2float(b23);
        acc.x += al2 * __low2float(c01); acc.y += al2 * __high2float(c01);
        acc.z += al2 * __low2float(c23); acc.w += al2 * __high2float(c23);
        acc.x += al3 * __low2float(d01); acc.y += al3 * __high2float(d01);
        acc.z += al3 * __low2float(d23); acc.w += al3 * __high2float(d23);
    }
    for (; j < end; ++j) {
        int src = adj[j];
        float e = a_src[src * HEADS + h2] + adst2;
        e = (e > 0.f) ? e : NEG_SLOPE * e;
        float alpha = __expf(e - mh) * inv;
        const __half2* p = reinterpret_cast<const __half2*>(&hW[(size_t)src * HID + lane4]);
        __half2 a01 = p[0], a23 = p[1];
        acc.x += alpha * __low2float(a01); acc.y += alpha * __high2float(a01);
        acc.z += alpha * __low2float(a23); acc.w += alpha * __high2float(a23);
    }

    float4 bv = *reinterpret_cast<const float4*>(&bias[lane4]);
    float4 o;
    o.x = acc.x + bv.x; o.y = acc.y + bv.y; o.z = acc.z + bv.z; o.w = acc.w + bv.w;
    o.x = (o.x > 0.f) ? o.x : expm1f(o.x);
    o.y = (o.y > 0.f) ? o.y : expm1f(o.y);
    o.z = (o.z > 0.f) ? o.z : expm1f(o.z);
    o.w = (o.w > 0.f) ? o.w : expm1f(o.w);
    ushort4 oh, ol;
    split_bf16(o.x, oh.x, ol.x);
    split_bf16(o.y, oh.y, ol.y);
    split_bf16(o.z, oh.z, ol.z);
    split_bf16(o.w, oh.w, ol.w);
    *reinterpret_cast<ushort4*>(&outhi[(size_t)n * HID + lane4]) = oh;
    *reinterpret_cast<ushort4*>(&outlo[(size_t)n * HID + lane4]) = ol;
}

// ------------------------------- CSR build ---------------------------------
__global__ void deg_count_kernel(const int* __restrict__ dst, int* __restrict__ deg, int E)
{
    for (int e = blockIdx.x * blockDim.x + threadIdx.x; e < E; e += gridDim.x * blockDim.x)
        atomicAdd(&deg[dst[e]], 1);
}

__global__ __launch_bounds__(256) void scan_block_kernel(
    const int* __restrict__ deg, int* __restrict__ row_ptr,
    int* __restrict__ blockSums, int n)
{
    __shared__ int sm[256];
    const int tid = threadIdx.x;
    const int i0 = blockIdx.x * 1024 + tid * 4;
    int v0 = (i0 + 0 < n) ? deg[i0 + 0] + 1 : 0;
    int v1 = (i0 + 1 < n) ? deg[i0 + 1] + 1 : 0;
    int v2 = (i0 + 2 < n) ? deg[i0 + 2] + 1 : 0;
    int v3 = (i0 + 3 < n) ? deg[i0 + 3] + 1 : 0;
    int s1 = v0 + v1, s2 = s1 + v2, s3 = s2 + v3;
    sm[tid] = s3;
    __syncthreads();
    #pragma unroll
    for (int off = 1; off < 256; off <<= 1) {
        int t = (tid >= off) ? sm[tid - off] : 0;
        __syncthreads();
        sm[tid] += t;
        __syncthreads();
    }
    int prev = (tid > 0) ? sm[tid - 1] : 0;
    if (tid == 255) blockSums[blockIdx.x] = sm[255];
    if (i0 + 0 < n) row_ptr[i0 + 1] = prev + v0;
    if (i0 + 1 < n) row_ptr[i0 + 2] = prev + s1;
    if (i0 + 2 < n) row_ptr[i0 + 3] = prev + s2;
    if (i0 + 3 < n) row_ptr[i0 + 4] = prev + s3;
}

__global__ void scan_sums_kernel(int* __restrict__ blockSums, int nb)
{
    const int lane = threadIdx.x;
    int v = (lane < nb) ? blockSums[lane] : 0;
    #pragma unroll
    for (int off = 1; off < 64; off <<= 1) {
        int t = __shfl_up(v, off);
        if (lane >= off) v += t;
    }
    if (lane < nb) blockSums[lane] = v;
}

__global__ __launch_bounds__(256) void scan_fixup_kernel(
    int* __restrict__ row_ptr, const int* __restrict__ blockSums, int n)
{
    int i = blockIdx.x * blockDim.x + threadIdx.x;
    if (i == 0) row_ptr[0] = 0;
    if (i < n) {
        int b = i >> 10;
        if (b > 0) row_ptr[i + 1] += blockSums[b - 1];
    }
}

__global__ void init_cursor_selfloop_kernel(
    const int* __restrict__ row_ptr, int* __restrict__ cursor,
    int* __restrict__ adj, int n)
{
    int i = blockIdx.x * blockDim.x + threadIdx.x;
    if (i < n) {
        int p = row_ptr[i];
        adj[p] = i;
        cursor[i] = p + 1;
    }
}

__global__ void edge_scatter_kernel(
    const int* __restrict__ src, const int* __restrict__ dst,
    int* __restrict__ cursor, int* __restrict__ adj, int E)
{
    for (int e = blockIdx.x * blockDim.x + threadIdx.x; e < E; e += gridDim.x * blockDim.x) {
        int pos = atomicAdd(&cursor[dst[e]], 1);
        adj[pos] = src[e];
    }
}

// ------------------------------- classifier --------------------------------
__global__ __launch_bounds__(256) void cls2_kernel(
    const float* __restrict__ hc, const float* __restrict__ W2,
    const float* __restrict__ b2, float* __restrict__ out, int n_nodes)
{
    const int wave = threadIdx.x >> 6;
    const int lane = threadIdx.x & 63;
    const int n = blockIdx.x * 4 + wave;
    if (n >= n_nodes) return;
    float h0 = hc[(size_t)n * 128 + lane];
    float h1 = hc[(size_t)n * 128 + 64 + lane];
    float p0 = h0 * W2[lane * 2 + 0] + h1 * W2[(64 + lane) * 2 + 0];
    float p1 = h0 * W2[lane * 2 + 1] + h1 * W2[(64 + lane) * 2 + 1];
    #pragma unroll
    for (int off = 1; off < 64; off <<= 1) {
        p0 += __shfl_xor(p0, off);
        p1 += __shfl_xor(p1, off);
    }
    if (lane == 0) {
        out[(size_t)n * 2 + 0] = p0 + b2[0];
        out[(size_t)n * 2 + 1] = p1 + b2[1];
    }
}

// ---------------------------------------------------------------------------
extern "C" void kernel_launch(void* const* d_in, const int* in_sizes, int n_in,
                              void* d_out, int out_size, void* d_ws, size_t ws_size,
                              hipStream_t stream)
{
    const float* x        = (const float*)d_in[0];
    const int*   tut_ei   = (const int*)d_in[1];
    const int*   tdt_ei   = (const int*)d_in[2];
    const float* proj_W   = (const float*)d_in[3];
    const float* proj_b   = (const float*)d_in[4];
    const float* tut_W    = (const float*)d_in[5];
    const float* tut_asrc = (const float*)d_in[6];
    const float* tut_adst = (const float*)d_in[7];
    const float* tut_bias = (const float*)d_in[8];
    const float* tdt_W    = (const float*)d_in[9];
    const float* tdt_asrc = (const float*)d_in[10];
    const float* tdt_adst = (const float*)d_in[11];
    const float* tdt_bias = (const float*)d_in[12];
    const float* sem_att  = (const float*)d_in[13];
    const float* cls_W1   = (const float*)d_in[14];
    const float* cls_b1   = (const float*)d_in[15];
    const float* cls_W2   = (const float*)d_in[16];
    const float* cls_b2   = (const float*)d_in[17];

    const int IN_CH = 128;
    const int N = in_sizes[0] / IN_CH;     // 50000
    const int E = in_sizes[1] / 2;         // 800000
    const size_t NH = (size_t)N * HID;     // 12.8M elems
    const size_t NI = (size_t)N * IN_CH;   // 6.4M elems

    // ------------------------ workspace layout ------------------------
    char* base = (char*)d_ws;
    size_t off = 0;
    auto alloc = [&](size_t bytes) -> void* {
        void* p = base + off;
        off = (off + bytes + 255) & ~(size_t)255;
        return p;
    };
    unsigned short* xhi  = (unsigned short*)alloc(NI * 2);   // also t2hi (first half)
    unsigned short* xlo  = (unsigned short*)alloc(NI * 2);   // also t2hi (second half)
    unsigned short* t2lo = (unsigned short*)alloc(NH * 2);
    unsigned short* h0hi = (unsigned short*)alloc(NH * 2);
    unsigned short* h0lo = (unsigned short*)alloc(NH * 2);
    unsigned short* l1hi = (unsigned short*)alloc(NH * 2);
    unsigned short* l1lo = (unsigned short*)alloc(NH * 2);
    __half*         hWf  = (__half*)alloc(NH * 2);           // also hc (fp32 N*128)
    float* a_src = (float*)alloc((size_t)N * HEADS * sizeof(float));
    float* a_dst = (float*)alloc((size_t)N * HEADS * sizeof(float));
    // transposed/split weights
    unsigned short* pWthi = (unsigned short*)alloc(256 * 128 * 2);
    unsigned short* pWtlo = (unsigned short*)alloc(256 * 128 * 2);
    unsigned short* tWthi = (unsigned short*)alloc(2 * 256 * 256 * 2);
    unsigned short* tWtlo = (unsigned short*)alloc(2 * 256 * 256 * 2);
    unsigned short* dWthi = (unsigned short*)alloc(2 * 256 * 256 * 2);
    unsigned short* dWtlo = (unsigned short*)alloc(2 * 256 * 256 * 2);
    unsigned short* cWthi = (unsigned short*)alloc(128 * 256 * 2);
    unsigned short* cWtlo = (unsigned short*)alloc(128 * 256 * 2);
    int* rp_tut  = (int*)alloc((size_t)(N + 1) * sizeof(int));
    int* adj_tut = (int*)alloc((size_t)(E + N) * sizeof(int));
    int* rp_tdt  = (int*)alloc((size_t)(N + 1) * sizeof(int));
    int* adj_tdt = (int*)alloc((size_t)(E + N) * sizeof(int));
    int* cursor  = (int*)alloc((size_t)N * sizeof(int));
    int* bsums   = (int*)alloc(256 * sizeof(int));
    (void)ws_size; (void)n_in; (void)out_size;

    unsigned short* t2hi = xhi;          // alias: x dead after proj GEMM
    unsigned short* d2hi = h0hi;         // alias: h0 dead after both layer-1 GEMMs
    unsigned short* d2lo = h0lo;
    unsigned short* zhi  = l1hi;         // alias: l1 dead after layer-2 GEMMs
    unsigned short* zlo  = l1lo;
    float*          hc   = (float*)hWf;  // alias: hW dead after last gat

    const int nodeBlocks = (N + 3) / 4;
    const int scanBlocks = (N + 1023) / 1024;

    // ---------------------------- CSR build ---------------------------
    auto build_csr = [&](const int* ei, int* row_ptr, int* adj) {
        hipMemsetAsync(cursor, 0, (size_t)N * sizeof(int), stream);
        deg_count_kernel<<<1024, 256, 0, stream>>>(ei + E, cursor, E);
        scan_block_kernel<<<scanBlocks, 256, 0, stream>>>(cursor, row_ptr, bsums, N);
        scan_sums_kernel<<<1, 64, 0, stream>>>(bsums, scanBlocks);
        scan_fixup_kernel<<<(N + 255) / 256, 256, 0, stream>>>(row_ptr, bsums, N);
        init_cursor_selfloop_kernel<<<(N + 255) / 256, 256, 0, stream>>>(row_ptr, cursor, adj, N);
        edge_scatter_kernel<<<1024, 256, 0, stream>>>(ei, ei + E, cursor, adj, E);
    };
    build_csr(tut_ei, rp_tut, adj_tut);
    build_csr(tdt_ei, rp_tdt, adj_tdt);

    // ------------------------ weight prep + x split -------------------
    transpose_split_kernel<<<(128 * 256 + 255) / 256, 256, 0, stream>>>(proj_W, pWthi, pWtlo, 128, 256);
    transpose_split_kernel<<<(256 * 256 + 255) / 256, 256, 0, stream>>>(tut_W, tWthi, tWtlo, 256, 256);
    transpose_split_kernel<<<(256 * 256 + 255) / 256, 256, 0, stream>>>(tut_W + 256 * 256, tWthi + 256 * 256, tWtlo + 256 * 256, 256, 256);
    transpose_split_kernel<<<(256 * 256 + 255) / 256, 256, 0, stream>>>(tdt_W, dWthi, dWtlo, 256, 256);
    transpose_split_kernel<<<(256 * 256 + 255) / 256, 256, 0, stream>>>(tdt_W + 256 * 256, dWthi + 256 * 256, dWtlo + 256 * 256, 256, 256);
    transpose_split_kernel<<<(256 * 128 + 255) / 256, 256, 0, stream>>>(cls_W1, cWthi, cWtlo, 256, 128);
    split4_kernel<<<(int)((NI / 4 + 255) / 256), 256, 0, stream>>>(x, xhi, xlo, (int)(NI / 4));

    const int gy = (N + 127) / 128;

    // ------------------------------ proj ------------------------------
    mfma_gemm_kernel<0><<<dim3(2, gy), 256, 0, stream>>>(
        xhi, xlo, pWthi, pWtlo, proj_b, h0hi, h0lo, nullptr, nullptr, N, HID, IN_CH);

    // ---------------------------- GAT layers --------------------------
    auto run_gat = [&](const unsigned short* ahi, const unsigned short* alo,
                       const unsigned short* wthi, const unsigned short* wtlo,
                       const float* asrc_w, const float* adst_w, const float* bias,
                       const int* row_ptr, const int* adj,
                       unsigned short* ohi, unsigned short* olo) {
        mfma_gemm_kernel<1><<<dim3(2, gy), 256, 0, stream>>>(
            ahi, alo, wthi, wtlo, nullptr, nullptr, nullptr, hWf, nullptr, N, HID, HID);
        att_kernel<<<nodeBlocks, 256, 0, stream>>>(hWf, asrc_w, adst_w, a_src, a_dst, N);
        gat_kernel<<<nodeBlocks, 256, 0, stream>>>(hWf, a_src, a_dst, row_ptr, adj, bias, ohi, olo, N);
    };

    const int WT = 256 * 256;     // transposed-weight stride per layer
    const int AS = HEADS * (HID / HEADS);

    run_gat(h0hi, h0lo, tWthi,      tWtlo,      tut_asrc,      tut_adst,      tut_bias,       rp_tut, adj_tut, l1hi, l1lo);
    run_gat(l1hi, l1lo, tWthi + WT, tWtlo + WT, tut_asrc + AS, tut_adst + AS, tut_bias + HID, rp_tut, adj_tut, t2hi, t2lo);
    run_gat(h0hi, h0lo, dWthi,      dWtlo,      tdt_asrc,      tdt_adst,      tdt_bias,       rp_tdt, adj_tdt, l1hi, l1lo);
    run_gat(l1hi, l1lo, dWthi + WT, dWtlo + WT, tdt_asrc + AS, tdt_adst + AS, tdt_bias + HID, rp_tdt, adj_tdt, d2hi, d2lo);

    // ------------------- combine + classifier -------------------------
    combine_split_kernel<<<(int)((NH / 4 + 255) / 256), 256, 0, stream>>>(
        t2hi, t2lo, d2hi, d2lo, sem_att, zhi, zlo, (int)(NH / 4));
    mfma_gemm_kernel<2><<<dim3(1, gy), 256, 0, stream>>>(
        zhi, zlo, cWthi, cWtlo, cls_b1, nullptr, nullptr, nullptr, hc, N, 128, HID);
    cls2_kernel<<<nodeBlocks, 256, 0, stream>>>(hc, cls_W2, cls_b2, (float*)d_out, N);
}

// Round 5
// 907.403 us; speedup vs baseline: 1.9191x; 1.0025x over previous
//
#include <hip/hip_runtime.h>
#include <hip/hip_fp16.h>
#include <cstddef>
#include <cstdint>

// ---------------------------------------------------------------------------
// SimpleHAN on MI355X — round 4:
//   - gat: single-pass flash-style online softmax (8 slots x 8 heads butterfly,
//     alpha computed once per (edge,head) and shfl-distributed to gather lanes)
//   - semantic combine fused into TDT layer-2 gat epilogue (OMODE=1)
//   - CSR build for both graphs merged into 6 dispatches; all weight prep +
//     x split into 1 kernel. 39 -> 22 dispatches total.
// ---------------------------------------------------------------------------

#define HID        256
#define HEADS      8
#define NEG_SLOPE  0.2f

typedef __attribute__((ext_vector_type(8))) short short8v;
typedef __attribute__((ext_vector_type(4))) float float4v;

static __device__ __forceinline__ unsigned short f32_to_bf16(float v) {
    union { float f; unsigned u; } c; c.f = v;
    unsigned r = c.u + 0x7FFFu + ((c.u >> 16) & 1u);
    return (unsigned short)(r >> 16);
}
static __device__ __forceinline__ float bf16_to_f32(unsigned short b) {
    union { unsigned u; float f; } c; c.u = ((unsigned)b) << 16;
    return c.f;
}
static __device__ __forceinline__ void split_bf16(float v, unsigned short& hi, unsigned short& lo) {
    hi = f32_to_bf16(v);
    lo = f32_to_bf16(v - bf16_to_f32(hi));
}
static __device__ __forceinline__ void gload_lds16(const void* g, void* l) {
    __builtin_amdgcn_global_load_lds((const __attribute__((address_space(1))) void*)g,
                                     (__attribute__((address_space(3))) void*)l, 16, 0, 0);
}

// ------------------------- MFMA GEMM (bf16x3 split) ------------------------
// C[M,N] = (Ahi+Alo)[M,K] @ (Bthi+Btlo)[N,K]^T  (+bias)
// MODE 0: split bf16 hi/lo (+bias). MODE 1: fp16. MODE 2: fp32+bias+relu.
template<int MODE>
__global__ __launch_bounds__(256) void mfma_gemm_kernel(
    const unsigned short* __restrict__ Ahi, const unsigned short* __restrict__ Alo,
    const unsigned short* __restrict__ Bthi, const unsigned short* __restrict__ Btlo,
    const float* __restrict__ bias,
    unsigned short* __restrict__ Chi, unsigned short* __restrict__ Clo,
    __half* __restrict__ Cf16, float* __restrict__ Cf32,
    int M, int N, int K)
{
    __shared__ __align__(16) short lds[4 * 4096];  // 32 KB

    const int tid  = threadIdx.x;
    const int lane = tid & 63;
    const int w    = tid >> 6;
    const int wr   = w >> 1;
    const int wc   = w & 1;
    const int m0   = blockIdx.y * 128;
    const int n0   = blockIdx.x * 128;

    const unsigned short* sbase = (w == 0) ? Ahi : (w == 1) ? Alo : (w == 2) ? Bthi : Btlo;
    const int rowbase = (w < 2) ? m0 : n0;
    const int rowlim  = ((w < 2) ? M : N) - 1;

    float4v acc[4][4];
    #pragma unroll
    for (int i = 0; i < 4; ++i)
        #pragma unroll
        for (int j = 0; j < 4; ++j)
            acc[i][j] = (float4v){0.f, 0.f, 0.f, 0.f};

    const int kcl = lane >> 4;
    const int rl  = lane & 15;

    for (int k0 = 0; k0 < K; k0 += 32) {
        #pragma unroll
        for (int rh = 0; rh < 2; ++rh) {
            int row = rowbase + rh * 64 + lane;
            row = row > rowlim ? rowlim : row;
            const unsigned short* src = sbase + (size_t)row * K + k0;
            #pragma unroll
            for (int kc = 0; kc < 4; ++kc) {
                short* dst = &lds[w * 4096 + kc * 1024 + rh * 512];
                gload_lds16(src + kc * 8, dst);
            }
        }
        __syncthreads();

        short8v ahi[4], alo[4], bhi[4], blo[4];
        #pragma unroll
        for (int i = 0; i < 4; ++i) {
            int am = wr * 64 + i * 16 + rl;
            int bn = wc * 64 + i * 16 + rl;
            ahi[i] = *(const short8v*)&lds[0 * 4096 + kcl * 1024 + am * 8];
            alo[i] = *(const short8v*)&lds[1 * 4096 + kcl * 1024 + am * 8];
            bhi[i] = *(const short8v*)&lds[2 * 4096 + kcl * 1024 + bn * 8];
            blo[i] = *(const short8v*)&lds[3 * 4096 + kcl * 1024 + bn * 8];
        }
        #pragma unroll
        for (int i = 0; i < 4; ++i)
            #pragma unroll
            for (int j = 0; j < 4; ++j) {
                acc[i][j] = __builtin_amdgcn_mfma_f32_16x16x32_bf16(ahi[i], bhi[j], acc[i][j], 0, 0, 0);
                acc[i][j] = __builtin_amdgcn_mfma_f32_16x16x32_bf16(ahi[i], blo[j], acc[i][j], 0, 0, 0);
                acc[i][j] = __builtin_amdgcn_mfma_f32_16x16x32_bf16(alo[i], bhi[j], acc[i][j], 0, 0, 0);
            }
        __syncthreads();
    }

    const int cr = (lane >> 4) * 4;
    #pragma unroll
    for (int i = 0; i < 4; ++i) {
        #pragma unroll
        for (int r = 0; r < 4; ++r) {
            int row = m0 + wr * 64 + i * 16 + cr + r;
            if (row >= M) continue;
            #pragma unroll
            for (int j = 0; j < 4; ++j) {
                int col = n0 + wc * 64 + j * 16 + rl;
                float v = acc[i][j][r];
                if (bias) v += bias[col];
                if (MODE == 0) {
                    unsigned short h, l;
                    split_bf16(v, h, l);
                    Chi[(size_t)row * N + col] = h;
                    Clo[(size_t)row * N + col] = l;
                } else if (MODE == 1) {
                    Cf16[(size_t)row * N + col] = __float2half(v);
                } else {
                    Cf32[(size_t)row * N + col] = fmaxf(v, 0.f);
                }
            }
        }
    }
}

// ----------------------- unified prep (weights + x) ------------------------
// transposes+splits 6 weight matrices and splits x, in one launch.
__global__ void prep_kernel(
    const float* __restrict__ proj_W, const float* __restrict__ tut_W,
    const float* __restrict__ tdt_W, const float* __restrict__ cls_W1,
    unsigned short* __restrict__ pWthi, unsigned short* __restrict__ pWtlo,
    unsigned short* __restrict__ tWthi, unsigned short* __restrict__ tWtlo,
    unsigned short* __restrict__ dWthi, unsigned short* __restrict__ dWtlo,
    unsigned short* __restrict__ cWthi, unsigned short* __restrict__ cWtlo,
    const float* __restrict__ x,
    unsigned short* __restrict__ xhi, unsigned short* __restrict__ xlo, int count4x)
{
    const int tid = blockIdx.x * blockDim.x + threadIdx.x;
    const int stride = gridDim.x * blockDim.x;
    // weights: proj 32768 | tut 2x65536 | tdt 2x65536 | cls 32768 = 327680
    for (int idx = tid; idx < 327680; idx += stride) {
        unsigned short h, l;
        if (idx < 32768) {
            int k = idx >> 8, n = idx & 255;               // K=128, N=256
            split_bf16(proj_W[idx], h, l);
            pWthi[n * 128 + k] = h; pWtlo[n * 128 + k] = l;
        } else if (idx < 163840) {
            int r = idx - 32768;
            int ly = r >> 16, rr = r & 65535;
            int k = rr >> 8, n = rr & 255;                 // K=256, N=256
            split_bf16(tut_W[r], h, l);
            tWthi[ly * 65536 + n * 256 + k] = h; tWtlo[ly * 65536 + n * 256 + k] = l;
        } else if (idx < 294912) {
            int r = idx - 163840;
            int ly = r >> 16, rr = r & 65535;
            int k = rr >> 8, n = rr & 255;
            split_bf16(tdt_W[r], h, l);
            dWthi[ly * 65536 + n * 256 + k] = h; dWtlo[ly * 65536 + n * 256 + k] = l;
        } else {
            int r = idx - 294912;
            int k = r >> 7, n = r & 127;                   // K=256, N=128
            split_bf16(cls_W1[r], h, l);
            cWthi[n * 256 + k] = h; cWtlo[n * 256 + k] = l;
        }
    }
    for (int i = tid; i < count4x; i += stride) {
        float4 v = reinterpret_cast<const float4*>(x)[i];
        ushort4 hh, ll;
        split_bf16(v.x, hh.x, ll.x);
        split_bf16(v.y, hh.y, ll.y);
        split_bf16(v.z, hh.z, ll.z);
        split_bf16(v.w, hh.w, ll.w);
        reinterpret_cast<ushort4*>(xhi)[i] = hh;
        reinterpret_cast<ushort4*>(xlo)[i] = ll;
    }
}

// ------------------------- attention dot products --------------------------
__global__ __launch_bounds__(256) void att_kernel(
    const __half* __restrict__ hW,
    const float* __restrict__ att_src, const float* __restrict__ att_dst,
    float* __restrict__ a_src, float* __restrict__ a_dst, int n_nodes)
{
    const int wave = threadIdx.x >> 6;
    const int lane = threadIdx.x & 63;
    const int n = blockIdx.x * 4 + wave;
    if (n >= n_nodes) return;

    const __half2* hp = reinterpret_cast<const __half2*>(&hW[(size_t)n * HID + lane * 4]);
    __half2 h01 = hp[0], h23 = hp[1];
    float hx = __low2float(h01), hy = __high2float(h01);
    float hz = __low2float(h23), hw = __high2float(h23);
    float4 s4 = *reinterpret_cast<const float4*>(&att_src[lane * 4]);
    float4 d4 = *reinterpret_cast<const float4*>(&att_dst[lane * 4]);
    float ps = hx * s4.x + hy * s4.y + hz * s4.z + hw * s4.w;
    float pd = hx * d4.x + hy * d4.y + hz * d4.z + hw * d4.w;
    #pragma unroll
    for (int off = 1; off < 8; off <<= 1) {
        ps += __shfl_xor(ps, off);
        pd += __shfl_xor(pd, off);
    }
    if ((lane & 7) == 0) {
        a_src[n * HEADS + (lane >> 3)] = ps;
        a_dst[n * HEADS + (lane >> 3)] = pd;
    }
}

// ----------------- GAT single-pass online softmax + gather -----------------
// One wave per dst node. Lane = (head h2 = lane>>3) x (slot sl = lane&7).
// Per 8-edge group: e computed once per (edge,head); butterfly xor{1,2,4}
// gives per-head group max/sum; p shfl-distributed to the head's 8 gather
// lanes. acc rescaled online (exact, deterministic).
// OMODE 0: write split bf16. OMODE 1: write z = w0*prev + w1*elu(out) split.
template<int OMODE>
__global__ __launch_bounds__(256) void gat_kernel(
    const __half* __restrict__ hW,
    const float* __restrict__ a_src, const float* __restrict__ a_dst,
    const int* __restrict__ row_ptr, const int* __restrict__ adj,
    const float* __restrict__ bias,
    const unsigned short* __restrict__ prevHi, const unsigned short* __restrict__ prevLo,
    const float* __restrict__ sem,
    unsigned short* __restrict__ outhi, unsigned short* __restrict__ outlo,
    int n_nodes)
{
    const int wave = threadIdx.x >> 6;
    const int lane = threadIdx.x & 63;
    const int n = blockIdx.x * 4 + wave;
    if (n >= n_nodes) return;

    const int beg = row_ptr[n];
    const int end = row_ptr[n + 1];
    const int h2 = lane >> 3;          // head (both roles)
    const int sl = lane & 7;           // edge slot
    const int lane4 = lane * 4;
    const int gbase = lane & 56;       // first lane of this head's group

    const float adst = a_dst[n * HEADS + h2];

    float m = -INFINITY, s = 0.f;
    float4 acc = make_float4(0.f, 0.f, 0.f, 0.f);

    for (int j = beg; j < end; j += 8) {
        const int js = j + sl;
        const int valid = js < end;
        int src_l = valid ? adj[js] : 0;
        float e = -INFINITY;
        if (valid) {
            e = a_src[src_l * HEADS + h2] + adst;
            e = (e > 0.f) ? e : NEG_SLOPE * e;
        }
        // per-head group max over the 8 slots
        float me = e;
        me = fmaxf(me, __shfl_xor(me, 1));
        me = fmaxf(me, __shfl_xor(me, 2));
        me = fmaxf(me, __shfl_xor(me, 4));
        const float m_new = fmaxf(m, me);
        const float scale = __expf(m - m_new);       // 0 on first group
        const float p = __expf(e - m_new);           // 0 for invalid slots
        float ps = p;
        ps += __shfl_xor(ps, 1);
        ps += __shfl_xor(ps, 2);
        ps += __shfl_xor(ps, 4);
        s = s * scale + ps;
        m = m_new;
        acc.x *= scale; acc.y *= scale; acc.z *= scale; acc.w *= scale;

        #pragma unroll
        for (int jj = 0; jj < 8; ++jj) {
            if (j + jj >= end) break;               // wave-uniform
            const float alpha = __shfl(p, gbase | jj);
            const int src = __shfl(src_l, jj);
            const __half2* hp = reinterpret_cast<const __half2*>(&hW[(size_t)src * HID + lane4]);
            __half2 v01 = hp[0], v23 = hp[1];
            acc.x += alpha * __low2float(v01);
            acc.y += alpha * __high2float(v01);
            acc.z += alpha * __low2float(v23);
            acc.w += alpha * __high2float(v23);
        }
    }

    const float inv = 1.f / (s + 1e-16f);
    float4 bv = *reinterpret_cast<const float4*>(&bias[lane4]);
    float4 o;
    o.x = acc.x * inv + bv.x; o.y = acc.y * inv + bv.y;
    o.z = acc.z * inv + bv.z; o.w = acc.w * inv + bv.w;
    o.x = (o.x > 0.f) ? o.x : expm1f(o.x);
    o.y = (o.y > 0.f) ? o.y : expm1f(o.y);
    o.z = (o.z > 0.f) ? o.z : expm1f(o.z);
    o.w = (o.w > 0.f) ? o.w : expm1f(o.w);

    if (OMODE == 1) {
        const float e0 = __expf(sem[0]);
        const float e1 = __expf(sem[1]);
        const float w0 = e0 / (e0 + e1);
        const float w1 = e1 / (e0 + e1);
        ushort4 ph = *reinterpret_cast<const ushort4*>(&prevHi[(size_t)n * HID + lane4]);
        ushort4 pl = *reinterpret_cast<const ushort4*>(&prevLo[(size_t)n * HID + lane4]);
        o.x = w0 * (bf16_to_f32(ph.x) + bf16_to_f32(pl.x)) + w1 * o.x;
        o.y = w0 * (bf16_to_f32(ph.y) + bf16_to_f32(pl.y)) + w1 * o.y;
        o.z = w0 * (bf16_to_f32(ph.z) + bf16_to_f32(pl.z)) + w1 * o.z;
        o.w = w0 * (bf16_to_f32(ph.w) + bf16_to_f32(pl.w)) + w1 * o.w;
    }

    ushort4 oh, ol;
    split_bf16(o.x, oh.x, ol.x);
    split_bf16(o.y, oh.y, ol.y);
    split_bf16(o.z, oh.z, ol.z);
    split_bf16(o.w, oh.w, ol.w);
    *reinterpret_cast<ushort4*>(&outhi[(size_t)n * HID + lane4]) = oh;
    *reinterpret_cast<ushort4*>(&outlo[(size_t)n * HID + lane4]) = ol;
}

// ----------------------- CSR build (both graphs) ---------------------------
__global__ void deg_count2_kernel(const int* __restrict__ tut_dst,
                                  const int* __restrict__ tdt_dst,
                                  int* __restrict__ deg, int E, int N)
{
    for (int e = blockIdx.x * blockDim.x + threadIdx.x; e < 2 * E; e += gridDim.x * blockDim.x) {
        if (e < E) atomicAdd(&deg[tut_dst[e]], 1);
        else       atomicAdd(&deg[N + tdt_dst[e - E]], 1);
    }
}

// stage 1: per-block (1024 elems) inclusive scan of deg+1 -> row_ptr[i+1] raw
__global__ __launch_bounds__(256) void scan_block_kernel(
    const int* __restrict__ deg, int* __restrict__ rp0, int* __restrict__ rp1,
    int* __restrict__ blockSums, int n)
{
    __shared__ int sm[256];
    const int y = blockIdx.y;
    const int* d = deg + (size_t)y * n;
    int* row_ptr = y ? rp1 : rp0;
    int* bsum = blockSums + y * 64;

    const int tid = threadIdx.x;
    const int i0 = blockIdx.x * 1024 + tid * 4;
    int v0 = (i0 + 0 < n) ? d[i0 + 0] + 1 : 0;
    int v1 = (i0 + 1 < n) ? d[i0 + 1] + 1 : 0;
    int v2 = (i0 + 2 < n) ? d[i0 + 2] + 1 : 0;
    int v3 = (i0 + 3 < n) ? d[i0 + 3] + 1 : 0;
    int s1 = v0 + v1, s2 = s1 + v2, s3 = s2 + v3;
    sm[tid] = s3;
    __syncthreads();
    #pragma unroll
    for (int off = 1; off < 256; off <<= 1) {
        int t = (tid >= off) ? sm[tid - off] : 0;
        __syncthreads();
        sm[tid] += t;
        __syncthreads();
    }
    int prev = (tid > 0) ? sm[tid - 1] : 0;
    if (tid == 255) bsum[blockIdx.x] = sm[255];
    if (i0 + 0 < n) row_ptr[i0 + 1] = prev + v0;
    if (i0 + 1 < n) row_ptr[i0 + 2] = prev + s1;
    if (i0 + 2 < n) row_ptr[i0 + 3] = prev + s2;
    if (i0 + 3 < n) row_ptr[i0 + 4] = prev + s3;
}

// stage 2: scan of 49 block sums; one block per graph
__global__ void scan_sums_kernel(int* __restrict__ blockSums, int nb)
{
    int* bs = blockSums + blockIdx.x * 64;
    const int lane = threadIdx.x;
    int v = (lane < nb) ? bs[lane] : 0;
    #pragma unroll
    for (int off = 1; off < 64; off <<= 1) {
        int t = __shfl_up(v, off);
        if (lane >= off) v += t;
    }
    if (lane < nb) bs[lane] = v;
}

// stage 3: carry fixup + self-loop init + cursor init (race-free: each thread
// derives its exclusive offset from its OWN inclusive value minus its count)
__global__ __launch_bounds__(256) void fixup_init_kernel(
    int* __restrict__ rp0, int* __restrict__ rp1,
    const int* __restrict__ blockSums, int* __restrict__ cursor,
    int* __restrict__ adj0, int* __restrict__ adj1, int n)
{
    const int y = blockIdx.y;
    int* rp = y ? rp1 : rp0;
    int* adj = y ? adj1 : adj0;
    const int* bs = blockSums + y * 64;
    int* cur = cursor + (size_t)y * n;

    const int i = blockIdx.x * blockDim.x + threadIdx.x;
    if (i >= n) return;
    const int degi = cur[i];
    const int b = i >> 10;
    const int fin = rp[i + 1] + (b > 0 ? bs[b - 1] : 0);
    rp[i + 1] = fin;
    if (i == 0) rp[0] = 0;
    const int p = fin - degi - 1;     // exclusive offset
    adj[p] = i;                       // self-loop first
    cur[i] = p + 1;
}

__global__ void edge_scatter2_kernel(
    const int* __restrict__ tut_ei, const int* __restrict__ tdt_ei,
    int* __restrict__ cursor, int* __restrict__ adj0, int* __restrict__ adj1,
    int E, int N)
{
    for (int e = blockIdx.x * blockDim.x + threadIdx.x; e < 2 * E; e += gridDim.x * blockDim.x) {
        if (e < E) {
            int pos = atomicAdd(&cursor[tut_ei[E + e]], 1);
            adj0[pos] = tut_ei[e];
        } else {
            int ee = e - E;
            int pos = atomicAdd(&cursor[N + tdt_ei[E + ee]], 1);
            adj1[pos] = tdt_ei[ee];
        }
    }
}

// ------------------------------- classifier --------------------------------
__global__ __launch_bounds__(256) void cls2_kernel(
    const float* __restrict__ hc, const float* __restrict__ W2,
    const float* __restrict__ b2, float* __restrict__ out, int n_nodes)
{
    const int wave = threadIdx.x >> 6;
    const int lane = threadIdx.x & 63;
    const int n = blockIdx.x * 4 + wave;
    if (n >= n_nodes) return;
    float h0 = hc[(size_t)n * 128 + lane];
    float h1 = hc[(size_t)n * 128 + 64 + lane];
    float p0 = h0 * W2[lane * 2 + 0] + h1 * W2[(64 + lane) * 2 + 0];
    float p1 = h0 * W2[lane * 2 + 1] + h1 * W2[(64 + lane) * 2 + 1];
    #pragma unroll
    for (int off = 1; off < 64; off <<= 1) {
        p0 += __shfl_xor(p0, off);
        p1 += __shfl_xor(p1, off);
    }
    if (lane == 0) {
        out[(size_t)n * 2 + 0] = p0 + b2[0];
        out[(size_t)n * 2 + 1] = p1 + b2[1];
    }
}

// ---------------------------------------------------------------------------
extern "C" void kernel_launch(void* const* d_in, const int* in_sizes, int n_in,
                              void* d_out, int out_size, void* d_ws, size_t ws_size,
                              hipStream_t stream)
{
    const float* x        = (const float*)d_in[0];
    const int*   tut_ei   = (const int*)d_in[1];
    const int*   tdt_ei   = (const int*)d_in[2];
    const float* proj_W   = (const float*)d_in[3];
    const float* proj_b   = (const float*)d_in[4];
    const float* tut_W    = (const float*)d_in[5];
    const float* tut_asrc = (const float*)d_in[6];
    const float* tut_adst = (const float*)d_in[7];
    const float* tut_bias = (const float*)d_in[8];
    const float* tdt_W    = (const float*)d_in[9];
    const float* tdt_asrc = (const float*)d_in[10];
    const float* tdt_adst = (const float*)d_in[11];
    const float* tdt_bias = (const float*)d_in[12];
    const float* sem_att  = (const float*)d_in[13];
    const float* cls_W1   = (const float*)d_in[14];
    const float* cls_b1   = (const float*)d_in[15];
    const float* cls_W2   = (const float*)d_in[16];
    const float* cls_b2   = (const float*)d_in[17];

    const int IN_CH = 128;
    const int N = in_sizes[0] / IN_CH;     // 50000
    const int E = in_sizes[1] / 2;         // 800000
    const size_t NH = (size_t)N * HID;
    const size_t NI = (size_t)N * IN_CH;

    // ------------------------ workspace layout ------------------------
    char* base = (char*)d_ws;
    size_t off = 0;
    auto alloc = [&](size_t bytes) -> void* {
        void* p = base + off;
        off = (off + bytes + 255) & ~(size_t)255;
        return p;
    };
    unsigned short* xhi  = (unsigned short*)alloc(NI * 2);   // + xlo = t2hi (contiguous)
    unsigned short* xlo  = (unsigned short*)alloc(NI * 2);
    unsigned short* t2lo = (unsigned short*)alloc(NH * 2);
    unsigned short* h0hi = (unsigned short*)alloc(NH * 2);
    unsigned short* h0lo = (unsigned short*)alloc(NH * 2);
    unsigned short* l1hi = (unsigned short*)alloc(NH * 2);
    unsigned short* l1lo = (unsigned short*)alloc(NH * 2);
    __half*         hWf  = (__half*)alloc(NH * 2);           // also hc (fp32 N*128)
    float* a_src = (float*)alloc((size_t)N * HEADS * sizeof(float));
    float* a_dst = (float*)alloc((size_t)N * HEADS * sizeof(float));
    unsigned short* pWthi = (unsigned short*)alloc(256 * 128 * 2);
    unsigned short* pWtlo = (unsigned short*)alloc(256 * 128 * 2);
    unsigned short* tWthi = (unsigned short*)alloc(2 * 256 * 256 * 2);
    unsigned short* tWtlo = (unsigned short*)alloc(2 * 256 * 256 * 2);
    unsigned short* dWthi = (unsigned short*)alloc(2 * 256 * 256 * 2);
    unsigned short* dWtlo = (unsigned short*)alloc(2 * 256 * 256 * 2);
    unsigned short* cWthi = (unsigned short*)alloc(128 * 256 * 2);
    unsigned short* cWtlo = (unsigned short*)alloc(128 * 256 * 2);
    int* rp_tut  = (int*)alloc((size_t)(N + 1) * sizeof(int));
    int* adj_tut = (int*)alloc((size_t)(E + N) * sizeof(int));
    int* rp_tdt  = (int*)alloc((size_t)(N + 1) * sizeof(int));
    int* adj_tdt = (int*)alloc((size_t)(E + N) * sizeof(int));
    int* cursor  = (int*)alloc((size_t)2 * N * sizeof(int)); // deg+cursor, both graphs
    int* bsums   = (int*)alloc(128 * sizeof(int));
    (void)ws_size; (void)n_in; (void)out_size;

    unsigned short* t2hi = xhi;          // alias: x dead after proj GEMM
    unsigned short* d2hi = h0hi;         // (d2 unused as separate now; TDT-L2 fuses)
    unsigned short* d2lo = h0lo;
    unsigned short* zhi  = l1hi;         // z written by fused TDT-L2 gat
    unsigned short* zlo  = l1lo;
    float*          hc   = (float*)hWf;
    (void)d2hi; (void)d2lo;

    const int nodeBlocks = (N + 3) / 4;
    const int scanBlocks = (N + 1023) / 1024;   // 49

    // --------------------- CSR build (both graphs) --------------------
    hipMemsetAsync(cursor, 0, (size_t)2 * N * sizeof(int), stream);
    prep_kernel<<<1024, 256, 0, stream>>>(proj_W, tut_W, tdt_W, cls_W1,
                                          pWthi, pWtlo, tWthi, tWtlo, dWthi, dWtlo,
                                          cWthi, cWtlo, x, xhi, xlo, (int)(NI / 4));
    deg_count2_kernel<<<2048, 256, 0, stream>>>(tut_ei + E, tdt_ei + E, cursor, E, N);
    scan_block_kernel<<<dim3(scanBlocks, 2), 256, 0, stream>>>(cursor, rp_tut, rp_tdt, bsums, N);
    scan_sums_kernel<<<2, 64, 0, stream>>>(bsums, scanBlocks);
    fixup_init_kernel<<<dim3((N + 255) / 256, 2), 256, 0, stream>>>(
        rp_tut, rp_tdt, bsums, cursor, adj_tut, adj_tdt, N);
    edge_scatter2_kernel<<<2048, 256, 0, stream>>>(tut_ei, tdt_ei, cursor, adj_tut, adj_tdt, E, N);

    const int gy = (N + 127) / 128;

    // ------------------------------ proj ------------------------------
    mfma_gemm_kernel<0><<<dim3(2, gy), 256, 0, stream>>>(
        xhi, xlo, pWthi, pWtlo, proj_b, h0hi, h0lo, nullptr, nullptr, N, HID, IN_CH);

    // ---------------------------- GAT layers --------------------------
    auto run_gemm_att = [&](const unsigned short* ahi, const unsigned short* alo,
                            const unsigned short* wthi, const unsigned short* wtlo,
                            const float* asrc_w, const float* adst_w) {
        mfma_gemm_kernel<1><<<dim3(2, gy), 256, 0, stream>>>(
            ahi, alo, wthi, wtlo, nullptr, nullptr, nullptr, hWf, nullptr, N, HID, HID);
        att_kernel<<<nodeBlocks, 256, 0, stream>>>(hWf, asrc_w, adst_w, a_src, a_dst, N);
    };

    const int WT = 256 * 256;
    const int AS = HEADS * (HID / HEADS);

    // TUT layer 1: h0 -> l1
    run_gemm_att(h0hi, h0lo, tWthi, tWtlo, tut_asrc, tut_adst);
    gat_kernel<0><<<nodeBlocks, 256, 0, stream>>>(
        hWf, a_src, a_dst, rp_tut, adj_tut, tut_bias,
        nullptr, nullptr, nullptr, l1hi, l1lo, N);
    // TUT layer 2: l1 -> t2
    run_gemm_att(l1hi, l1lo, tWthi + WT, tWtlo + WT, tut_asrc + AS, tut_adst + AS);
    gat_kernel<0><<<nodeBlocks, 256, 0, stream>>>(
        hWf, a_src, a_dst, rp_tut, adj_tut, tut_bias + HID,
        nullptr, nullptr, nullptr, t2hi, t2lo, N);
    // TDT layer 1: h0 -> l1
    run_gemm_att(h0hi, h0lo, dWthi, dWtlo, tdt_asrc, tdt_adst);
    gat_kernel<0><<<nodeBlocks, 256, 0, stream>>>(
        hWf, a_src, a_dst, rp_tdt, adj_tdt, tdt_bias,
        nullptr, nullptr, nullptr, l1hi, l1lo, N);
    // TDT layer 2 (fused semantic combine): z = w0*t2 + w1*elu(gat)
    run_gemm_att(l1hi, l1lo, dWthi + WT, dWtlo + WT, tdt_asrc + AS, tdt_adst + AS);
    gat_kernel<1><<<nodeBlocks, 256, 0, stream>>>(
        hWf, a_src, a_dst, rp_tdt, adj_tdt, tdt_bias + HID,
        t2hi, t2lo, sem_att, zhi, zlo, N);

    // --------------------------- classifier ---------------------------
    mfma_gemm_kernel<2><<<dim3(1, gy), 256, 0, stream>>>(
        zhi, zlo, cWthi, cWtlo, cls_b1, nullptr, nullptr, nullptr, hc, N, 128, HID);
    cls2_kernel<<<nodeBlocks, 256, 0, stream>>>(hc, cls_W2, cls_b2, (float*)d_out, N);
}

// Round 7
// 759.283 us; speedup vs baseline: 2.2935x; 1.1951x over previous
//
#include <hip/hip_runtime.h>
#include <hip/hip_fp16.h>
#include <cstddef>
#include <cstdint>

// ---------------------------------------------------------------------------
// SimpleHAN on MI355X — round 6 (round 5 + crash fix):
//   BUG was: gcount/gcursor zeroed with one memset across the allocator's
//   256B-alignment padding -> last 50 gcursor ints uninitialized -> wild
//   int2 scatter in bucket_bin. Now one contiguous 4*NB block, exact memset.
//   Also: ebuf aliases hWf (dead before first GEMM), lhist fully initialized.
// ---------------------------------------------------------------------------

#define HID        256
#define HEADS      8
#define NEG_SLOPE  0.2f

#define BSH     7          // bucket shift: 128 nodes per bucket
#define BNODES  128
#define MAXNB   512        // scan width (NB = 391 for N = 50000)
#define CH      2048       // edges per bin chunk

typedef __attribute__((ext_vector_type(8))) short short8v;
typedef __attribute__((ext_vector_type(4))) float float4v;

static __device__ __forceinline__ unsigned short f32_to_bf16(float v) {
    union { float f; unsigned u; } c; c.f = v;
    unsigned r = c.u + 0x7FFFu + ((c.u >> 16) & 1u);
    return (unsigned short)(r >> 16);
}
static __device__ __forceinline__ float bf16_to_f32(unsigned short b) {
    union { unsigned u; float f; } c; c.u = ((unsigned)b) << 16;
    return c.f;
}
static __device__ __forceinline__ void split_bf16(float v, unsigned short& hi, unsigned short& lo) {
    hi = f32_to_bf16(v);
    lo = f32_to_bf16(v - bf16_to_f32(hi));
}
static __device__ __forceinline__ void gload_lds16(const void* g, void* l) {
    __builtin_amdgcn_global_load_lds((const __attribute__((address_space(1))) void*)g,
                                     (__attribute__((address_space(3))) void*)l, 16, 0, 0);
}

// ------------------------- MFMA GEMM (bf16x3 split) ------------------------
// C[M,N] = (Ahi+Alo)[M,K] @ (Bthi+Btlo)[N,K]^T  (+bias)
// MODE 0: split bf16 hi/lo (+bias). MODE 1: fp16. MODE 2: fp32+bias+relu.
template<int MODE>
__global__ __launch_bounds__(256) void mfma_gemm_kernel(
    const unsigned short* __restrict__ Ahi, const unsigned short* __restrict__ Alo,
    const unsigned short* __restrict__ Bthi, const unsigned short* __restrict__ Btlo,
    const float* __restrict__ bias,
    unsigned short* __restrict__ Chi, unsigned short* __restrict__ Clo,
    __half* __restrict__ Cf16, float* __restrict__ Cf32,
    int M, int N, int K)
{
    __shared__ __align__(16) short lds[4 * 4096];  // 32 KB

    const int tid  = threadIdx.x;
    const int lane = tid & 63;
    const int w    = tid >> 6;
    const int wr   = w >> 1;
    const int wc   = w & 1;
    const int m0   = blockIdx.y * 128;
    const int n0   = blockIdx.x * 128;

    const unsigned short* sbase = (w == 0) ? Ahi : (w == 1) ? Alo : (w == 2) ? Bthi : Btlo;
    const int rowbase = (w < 2) ? m0 : n0;
    const int rowlim  = ((w < 2) ? M : N) - 1;

    float4v acc[4][4];
    #pragma unroll
    for (int i = 0; i < 4; ++i)
        #pragma unroll
        for (int j = 0; j < 4; ++j)
            acc[i][j] = (float4v){0.f, 0.f, 0.f, 0.f};

    const int kcl = lane >> 4;
    const int rl  = lane & 15;

    for (int k0 = 0; k0 < K; k0 += 32) {
        #pragma unroll
        for (int rh = 0; rh < 2; ++rh) {
            int row = rowbase + rh * 64 + lane;
            row = row > rowlim ? rowlim : row;
            const unsigned short* src = sbase + (size_t)row * K + k0;
            #pragma unroll
            for (int kc = 0; kc < 4; ++kc) {
                short* dst = &lds[w * 4096 + kc * 1024 + rh * 512];
                gload_lds16(src + kc * 8, dst);
            }
        }
        __syncthreads();

        short8v ahi[4], alo[4], bhi[4], blo[4];
        #pragma unroll
        for (int i = 0; i < 4; ++i) {
            int am = wr * 64 + i * 16 + rl;
            int bn = wc * 64 + i * 16 + rl;
            ahi[i] = *(const short8v*)&lds[0 * 4096 + kcl * 1024 + am * 8];
            alo[i] = *(const short8v*)&lds[1 * 4096 + kcl * 1024 + am * 8];
            bhi[i] = *(const short8v*)&lds[2 * 4096 + kcl * 1024 + bn * 8];
            blo[i] = *(const short8v*)&lds[3 * 4096 + kcl * 1024 + bn * 8];
        }
        #pragma unroll
        for (int i = 0; i < 4; ++i)
            #pragma unroll
            for (int j = 0; j < 4; ++j) {
                acc[i][j] = __builtin_amdgcn_mfma_f32_16x16x32_bf16(ahi[i], bhi[j], acc[i][j], 0, 0, 0);
                acc[i][j] = __builtin_amdgcn_mfma_f32_16x16x32_bf16(ahi[i], blo[j], acc[i][j], 0, 0, 0);
                acc[i][j] = __builtin_amdgcn_mfma_f32_16x16x32_bf16(alo[i], bhi[j], acc[i][j], 0, 0, 0);
            }
        __syncthreads();
    }

    const int cr = (lane >> 4) * 4;
    #pragma unroll
    for (int i = 0; i < 4; ++i) {
        #pragma unroll
        for (int r = 0; r < 4; ++r) {
            int row = m0 + wr * 64 + i * 16 + cr + r;
            if (row >= M) continue;
            #pragma unroll
            for (int j = 0; j < 4; ++j) {
                int col = n0 + wc * 64 + j * 16 + rl;
                float v = acc[i][j][r];
                if (bias) v += bias[col];
                if (MODE == 0) {
                    unsigned short h, l;
                    split_bf16(v, h, l);
                    Chi[(size_t)row * N + col] = h;
                    Clo[(size_t)row * N + col] = l;
                } else if (MODE == 1) {
                    Cf16[(size_t)row * N + col] = __float2half(v);
                } else {
                    Cf32[(size_t)row * N + col] = fmaxf(v, 0.f);
                }
            }
        }
    }
}

// ----------------------- unified prep (weights + x) ------------------------
__global__ void prep_kernel(
    const float* __restrict__ proj_W, const float* __restrict__ tut_W,
    const float* __restrict__ tdt_W, const float* __restrict__ cls_W1,
    unsigned short* __restrict__ pWthi, unsigned short* __restrict__ pWtlo,
    unsigned short* __restrict__ tWthi, unsigned short* __restrict__ tWtlo,
    unsigned short* __restrict__ dWthi, unsigned short* __restrict__ dWtlo,
    unsigned short* __restrict__ cWthi, unsigned short* __restrict__ cWtlo,
    const float* __restrict__ x,
    unsigned short* __restrict__ xhi, unsigned short* __restrict__ xlo, int count4x)
{
    const int tid = blockIdx.x * blockDim.x + threadIdx.x;
    const int stride = gridDim.x * blockDim.x;
    for (int idx = tid; idx < 327680; idx += stride) {
        unsigned short h, l;
        if (idx < 32768) {
            int k = idx >> 8, n = idx & 255;
            split_bf16(proj_W[idx], h, l);
            pWthi[n * 128 + k] = h; pWtlo[n * 128 + k] = l;
        } else if (idx < 163840) {
            int r = idx - 32768;
            int ly = r >> 16, rr = r & 65535;
            int k = rr >> 8, n = rr & 255;
            split_bf16(tut_W[r], h, l);
            tWthi[ly * 65536 + n * 256 + k] = h; tWtlo[ly * 65536 + n * 256 + k] = l;
        } else if (idx < 294912) {
            int r = idx - 163840;
            int ly = r >> 16, rr = r & 65535;
            int k = rr >> 8, n = rr & 255;
            split_bf16(tdt_W[r], h, l);
            dWthi[ly * 65536 + n * 256 + k] = h; dWtlo[ly * 65536 + n * 256 + k] = l;
        } else {
            int r = idx - 294912;
            int k = r >> 7, n = r & 127;
            split_bf16(cls_W1[r], h, l);
            cWthi[n * 256 + k] = h; cWtlo[n * 256 + k] = l;
        }
    }
    for (int i = tid; i < count4x; i += stride) {
        float4 v = reinterpret_cast<const float4*>(x)[i];
        ushort4 hh, ll;
        split_bf16(v.x, hh.x, ll.x);
        split_bf16(v.y, hh.y, ll.y);
        split_bf16(v.z, hh.z, ll.z);
        split_bf16(v.w, hh.w, ll.w);
        reinterpret_cast<ushort4*>(xhi)[i] = hh;
        reinterpret_cast<ushort4*>(xlo)[i] = ll;
    }
}

// ------------------------- attention dot products --------------------------
__global__ __launch_bounds__(256) void att_kernel(
    const __half* __restrict__ hW,
    const float* __restrict__ att_src, const float* __restrict__ att_dst,
    float* __restrict__ a_src, float* __restrict__ a_dst, int n_nodes)
{
    const int wave = threadIdx.x >> 6;
    const int lane = threadIdx.x & 63;
    const int n = blockIdx.x * 4 + wave;
    if (n >= n_nodes) return;

    const __half2* hp = reinterpret_cast<const __half2*>(&hW[(size_t)n * HID + lane * 4]);
    __half2 h01 = hp[0], h23 = hp[1];
    float hx = __low2float(h01), hy = __high2float(h01);
    float hz = __low2float(h23), hw = __high2float(h23);
    float4 s4 = *reinterpret_cast<const float4*>(&att_src[lane * 4]);
    float4 d4 = *reinterpret_cast<const float4*>(&att_dst[lane * 4]);
    float ps = hx * s4.x + hy * s4.y + hz * s4.z + hw * s4.w;
    float pd = hx * d4.x + hy * d4.y + hz * d4.z + hw * d4.w;
    #pragma unroll
    for (int off = 1; off < 8; off <<= 1) {
        ps += __shfl_xor(ps, off);
        pd += __shfl_xor(pd, off);
    }
    if ((lane & 7) == 0) {
        a_src[n * HEADS + (lane >> 3)] = ps;
        a_dst[n * HEADS + (lane >> 3)] = pd;
    }
}

// ----------------- GAT single-pass online softmax + gather -----------------
template<int OMODE>
__global__ __launch_bounds__(256) void gat_kernel(
    const __half* __restrict__ hW,
    const float* __restrict__ a_src, const float* __restrict__ a_dst,
    const int* __restrict__ row_ptr, const int* __restrict__ adj,
    const float* __restrict__ bias,
    const unsigned short* __restrict__ prevHi, const unsigned short* __restrict__ prevLo,
    const float* __restrict__ sem,
    unsigned short* __restrict__ outhi, unsigned short* __restrict__ outlo,
    int n_nodes)
{
    const int wave = threadIdx.x >> 6;
    const int lane = threadIdx.x & 63;
    const int n = blockIdx.x * 4 + wave;
    if (n >= n_nodes) return;

    const int beg = row_ptr[n];
    const int end = row_ptr[n + 1];
    const int h2 = lane >> 3;
    const int sl = lane & 7;
    const int lane4 = lane * 4;
    const int gbase = lane & 56;

    const float adst = a_dst[n * HEADS + h2];

    float m = -INFINITY, s = 0.f;
    float4 acc = make_float4(0.f, 0.f, 0.f, 0.f);

    for (int j = beg; j < end; j += 8) {
        const int js = j + sl;
        const int valid = js < end;
        int src_l = valid ? adj[js] : 0;
        float e = -INFINITY;
        if (valid) {
            e = a_src[src_l * HEADS + h2] + adst;
            e = (e > 0.f) ? e : NEG_SLOPE * e;
        }
        float me = e;
        me = fmaxf(me, __shfl_xor(me, 1));
        me = fmaxf(me, __shfl_xor(me, 2));
        me = fmaxf(me, __shfl_xor(me, 4));
        const float m_new = fmaxf(m, me);
        const float scale = __expf(m - m_new);
        const float p = __expf(e - m_new);
        float ps = p;
        ps += __shfl_xor(ps, 1);
        ps += __shfl_xor(ps, 2);
        ps += __shfl_xor(ps, 4);
        s = s * scale + ps;
        m = m_new;
        acc.x *= scale; acc.y *= scale; acc.z *= scale; acc.w *= scale;

        #pragma unroll
        for (int jj = 0; jj < 8; ++jj) {
            if (j + jj >= end) break;
            const float alpha = __shfl(p, gbase | jj);
            const int src = __shfl(src_l, jj);
            const __half2* hp = reinterpret_cast<const __half2*>(&hW[(size_t)src * HID + lane4]);
            __half2 v01 = hp[0], v23 = hp[1];
            acc.x += alpha * __low2float(v01);
            acc.y += alpha * __high2float(v01);
            acc.z += alpha * __low2float(v23);
            acc.w += alpha * __high2float(v23);
        }
    }

    const float inv = 1.f / (s + 1e-16f);
    float4 bv = *reinterpret_cast<const float4*>(&bias[lane4]);
    float4 o;
    o.x = acc.x * inv + bv.x; o.y = acc.y * inv + bv.y;
    o.z = acc.z * inv + bv.z; o.w = acc.w * inv + bv.w;
    o.x = (o.x > 0.f) ? o.x : expm1f(o.x);
    o.y = (o.y > 0.f) ? o.y : expm1f(o.y);
    o.z = (o.z > 0.f) ? o.z : expm1f(o.z);
    o.w = (o.w > 0.f) ? o.w : expm1f(o.w);

    if (OMODE == 1) {
        const float e0 = __expf(sem[0]);
        const float e1 = __expf(sem[1]);
        const float w0 = e0 / (e0 + e1);
        const float w1 = e1 / (e0 + e1);
        ushort4 ph = *reinterpret_cast<const ushort4*>(&prevHi[(size_t)n * HID + lane4]);
        ushort4 pl = *reinterpret_cast<const ushort4*>(&prevLo[(size_t)n * HID + lane4]);
        o.x = w0 * (bf16_to_f32(ph.x) + bf16_to_f32(pl.x)) + w1 * o.x;
        o.y = w0 * (bf16_to_f32(ph.y) + bf16_to_f32(pl.y)) + w1 * o.y;
        o.z = w0 * (bf16_to_f32(ph.z) + bf16_to_f32(pl.z)) + w1 * o.z;
        o.w = w0 * (bf16_to_f32(ph.w) + bf16_to_f32(pl.w)) + w1 * o.w;
    }

    ushort4 oh, ol;
    split_bf16(o.x, oh.x, ol.x);
    split_bf16(o.y, oh.y, ol.y);
    split_bf16(o.z, oh.z, ol.z);
    split_bf16(o.w, oh.w, ol.w);
    *reinterpret_cast<ushort4*>(&outhi[(size_t)n * HID + lane4]) = oh;
    *reinterpret_cast<ushort4*>(&outlo[(size_t)n * HID + lane4]) = ol;
}

// ------------------- CSR build: bucketed counting sort ---------------------
// Pass A: bucket histogram (LDS-aggregated)
__global__ __launch_bounds__(256) void bucket_count_kernel(
    const int* __restrict__ tut_dst, const int* __restrict__ tdt_dst,
    int* __restrict__ gcount, int E, int NB)
{
    __shared__ int hist[MAXNB];
    const int g = blockIdx.y;
    const int* dstp = g ? tdt_dst : tut_dst;
    for (int i = threadIdx.x; i < MAXNB; i += 256) hist[i] = 0;
    __syncthreads();
    for (int e = blockIdx.x * 256 + threadIdx.x; e < E; e += gridDim.x * 256)
        atomicAdd(&hist[dstp[e] >> BSH], 1);
    __syncthreads();
    for (int i = threadIdx.x; i < NB; i += 256) {
        int c = hist[i];
        if (c) atomicAdd(&gcount[g * NB + i], c);
    }
}

// Scan: bucket counts -> edge-staging bases (ebase) and adj bases (adjbase).
__global__ __launch_bounds__(512) void bucket_scan_kernel(
    const int* __restrict__ gcount, int* __restrict__ ebase, int* __restrict__ adjbase,
    int* __restrict__ rp0, int* __restrict__ rp1, int N, int E, int NB)
{
    __shared__ int sa[MAXNB], sb[MAXNB];
    const int t = threadIdx.x;
    for (int g = 0; g < 2; ++g) {
        int cnt = (t < NB) ? gcount[g * NB + t] : 0;
        int nodes = 0;
        if (t < NB) { int s = t << BSH; nodes = (N - s < BNODES) ? (N - s) : BNODES; }
        sa[t] = cnt;
        sb[t] = cnt + nodes;
        __syncthreads();
        for (int off = 1; off < MAXNB; off <<= 1) {
            int va = (t >= off) ? sa[t - off] : 0;
            int vb = (t >= off) ? sb[t - off] : 0;
            __syncthreads();
            sa[t] += va; sb[t] += vb;
            __syncthreads();
        }
        if (t < NB) {
            ebase[g * (NB + 1) + t + 1] = sa[t];
            adjbase[g * (NB + 1) + t + 1] = sb[t];
        }
        if (t == 0) { ebase[g * (NB + 1)] = 0; adjbase[g * (NB + 1)] = 0; }
        __syncthreads();
    }
    if (t == 0) { rp0[N] = E + N; rp1[N] = E + N; }
}

// Pass B: bin edges into bucket-contiguous staging (chunk LDS-sort + run dump)
__global__ __launch_bounds__(256) void bucket_bin_kernel(
    const int* __restrict__ tut_ei, const int* __restrict__ tdt_ei,
    const int* __restrict__ ebase, int* __restrict__ gcursor,
    int2* __restrict__ ebuf, int E, int NB)
{
    __shared__ int lhist[MAXNB];
    __shared__ int lbase[MAXNB];
    __shared__ int loffs[MAXNB];
    __shared__ int2 spair[CH];
    __shared__ int saddr[CH];
    const int g = blockIdx.y;
    const int* ei = g ? tdt_ei : tut_ei;
    const int e0 = blockIdx.x * CH;
    const int cnt = (E - e0 < CH) ? (E - e0) : CH;

    for (int i = threadIdx.x; i < MAXNB; i += 256) lhist[i] = 0;
    __syncthreads();

    int myb[8], myrank[8], mysrc[8], mydst[8];
    int nmine = 0;
    #pragma unroll
    for (int k = 0; k < 8; ++k) {
        int idx = e0 + threadIdx.x + k * 256;
        if (idx < e0 + cnt) {
            int sv = ei[idx];
            int dv = ei[E + idx];
            int b = dv >> BSH;
            int r = atomicAdd(&lhist[b], 1);
            myb[nmine] = b; myrank[nmine] = r; mysrc[nmine] = sv; mydst[nmine] = dv;
            ++nmine;
        }
    }
    __syncthreads();
    loffs[threadIdx.x] = lhist[threadIdx.x];
    loffs[threadIdx.x + 256] = lhist[threadIdx.x + 256];
    __syncthreads();
    for (int off = 1; off < MAXNB; off <<= 1) {
        int i0 = threadIdx.x, i1 = threadIdx.x + 256;
        int v0 = (i0 >= off) ? loffs[i0 - off] : 0;
        int v1 = (i1 >= off) ? loffs[i1 - off] : 0;
        __syncthreads();
        loffs[i0] += v0; loffs[i1] += v1;
        __syncthreads();
    }
    for (int i = threadIdx.x; i < NB; i += 256) {
        int c = lhist[i];
        lbase[i] = c ? atomicAdd(&gcursor[g * NB + i], c) : 0;
    }
    __syncthreads();
    const int* eb = ebase + g * (NB + 1);
    for (int k = 0; k < nmine; ++k) {
        int b = myb[k];
        int sorted = loffs[b] - lhist[b] + myrank[k];
        spair[sorted] = make_int2(mysrc[k], mydst[k]);
        saddr[sorted] = eb[b] + lbase[b] + myrank[k];
    }
    __syncthreads();
    int2* out = ebuf + (size_t)g * E;
    for (int i = threadIdx.x; i < cnt; i += 256)
        out[saddr[i]] = spair[i];
}

// Pass C: one block per bucket -> local CSR in LDS, contiguous writes.
__global__ __launch_bounds__(256) void bucket_csr_kernel(
    const int* __restrict__ gcount, const int* __restrict__ ebase,
    const int* __restrict__ adjbase, const int2* __restrict__ ebuf,
    int* __restrict__ rp0, int* __restrict__ rp1,
    int* __restrict__ adj0, int* __restrict__ adj1, int N, int E, int NB)
{
    __shared__ int hist[BNODES], scn[BNODES], cursor[BNODES];
    const int g = blockIdx.y;
    const int b = blockIdx.x;
    int* rp  = g ? rp1 : rp0;
    int* adj = g ? adj1 : adj0;
    const int cnt = gcount[g * NB + b];
    const int aB  = adjbase[g * (NB + 1) + b];
    const int node0 = b << BSH;
    const int nb = (N - node0 < BNODES) ? (N - node0) : BNODES;
    const int2* ep = ebuf + (size_t)g * E + ebase[g * (NB + 1) + b];
    const int t = threadIdx.x;

    if (t < BNODES) hist[t] = 0;
    __syncthreads();
    for (int e = t; e < cnt; e += 256)
        atomicAdd(&hist[ep[e].y - node0], 1);
    __syncthreads();
    if (t < BNODES) scn[t] = (t < nb) ? hist[t] + 1 : 0;
    __syncthreads();
    for (int off = 1; off < BNODES; off <<= 1) {
        int v = 0;
        if (t < BNODES && t >= off) v = scn[t - off];
        __syncthreads();
        if (t < BNODES) scn[t] += v;
        __syncthreads();
    }
    if (t < nb) {
        int s = scn[t] - hist[t] - 1;       // exclusive offset
        rp[node0 + t] = aB + s;
        adj[aB + s] = node0 + t;            // self-loop first
        cursor[t] = s + 1;
    }
    __syncthreads();
    for (int e = t; e < cnt; e += 256) {
        int2 pr = ep[e];
        int pos = atomicAdd(&cursor[pr.y - node0], 1);
        adj[aB + pos] = pr.x;
    }
}

// ------------------------------- classifier --------------------------------
__global__ __launch_bounds__(256) void cls2_kernel(
    const float* __restrict__ hc, const float* __restrict__ W2,
    const float* __restrict__ b2, float* __restrict__ out, int n_nodes)
{
    const int wave = threadIdx.x >> 6;
    const int lane = threadIdx.x & 63;
    const int n = blockIdx.x * 4 + wave;
    if (n >= n_nodes) return;
    float h0 = hc[(size_t)n * 128 + lane];
    float h1 = hc[(size_t)n * 128 + 64 + lane];
    float p0 = h0 * W2[lane * 2 + 0] + h1 * W2[(64 + lane) * 2 + 0];
    float p1 = h0 * W2[lane * 2 + 1] + h1 * W2[(64 + lane) * 2 + 1];
    #pragma unroll
    for (int off = 1; off < 64; off <<= 1) {
        p0 += __shfl_xor(p0, off);
        p1 += __shfl_xor(p1, off);
    }
    if (lane == 0) {
        out[(size_t)n * 2 + 0] = p0 + b2[0];
        out[(size_t)n * 2 + 1] = p1 + b2[1];
    }
}

// ---------------------------------------------------------------------------
extern "C" void kernel_launch(void* const* d_in, const int* in_sizes, int n_in,
                              void* d_out, int out_size, void* d_ws, size_t ws_size,
                              hipStream_t stream)
{
    const float* x        = (const float*)d_in[0];
    const int*   tut_ei   = (const int*)d_in[1];
    const int*   tdt_ei   = (const int*)d_in[2];
    const float* proj_W   = (const float*)d_in[3];
    const float* proj_b   = (const float*)d_in[4];
    const float* tut_W    = (const float*)d_in[5];
    const float* tut_asrc = (const float*)d_in[6];
    const float* tut_adst = (const float*)d_in[7];
    const float* tut_bias = (const float*)d_in[8];
    const float* tdt_W    = (const float*)d_in[9];
    const float* tdt_asrc = (const float*)d_in[10];
    const float* tdt_adst = (const float*)d_in[11];
    const float* tdt_bias = (const float*)d_in[12];
    const float* sem_att  = (const float*)d_in[13];
    const float* cls_W1   = (const float*)d_in[14];
    const float* cls_b1   = (const float*)d_in[15];
    const float* cls_W2   = (const float*)d_in[16];
    const float* cls_b2   = (const float*)d_in[17];

    const int IN_CH = 128;
    const int N = in_sizes[0] / IN_CH;     // 50000
    const int E = in_sizes[1] / 2;         // 800000
    const int NB = (N + BNODES - 1) >> BSH; // 391
    const size_t NH = (size_t)N * HID;
    const size_t NI = (size_t)N * IN_CH;

    // ------------------------ workspace layout ------------------------
    char* base = (char*)d_ws;
    size_t off = 0;
    auto alloc = [&](size_t bytes) -> void* {
        void* p = base + off;
        off = (off + bytes + 255) & ~(size_t)255;
        return p;
    };
    unsigned short* xhi  = (unsigned short*)alloc(NI * 2);
    unsigned short* xlo  = (unsigned short*)alloc(NI * 2);
    unsigned short* t2lo = (unsigned short*)alloc(NH * 2);
    unsigned short* h0hi = (unsigned short*)alloc(NH * 2);
    unsigned short* h0lo = (unsigned short*)alloc(NH * 2);
    unsigned short* l1hi = (unsigned short*)alloc(NH * 2);
    unsigned short* l1lo = (unsigned short*)alloc(NH * 2);
    __half*         hWf  = (__half*)alloc(NH * 2);           // 25.6MB; ebuf aliases
    float* a_src = (float*)alloc((size_t)N * HEADS * sizeof(float));
    float* a_dst = (float*)alloc((size_t)N * HEADS * sizeof(float));
    unsigned short* pWthi = (unsigned short*)alloc(256 * 128 * 2);
    unsigned short* pWtlo = (unsigned short*)alloc(256 * 128 * 2);
    unsigned short* tWthi = (unsigned short*)alloc(2 * 256 * 256 * 2);
    unsigned short* tWtlo = (unsigned short*)alloc(2 * 256 * 256 * 2);
    unsigned short* dWthi = (unsigned short*)alloc(2 * 256 * 256 * 2);
    unsigned short* dWtlo = (unsigned short*)alloc(2 * 256 * 256 * 2);
    unsigned short* cWthi = (unsigned short*)alloc(128 * 256 * 2);
    unsigned short* cWtlo = (unsigned short*)alloc(128 * 256 * 2);
    int* rp_tut  = (int*)alloc((size_t)(N + 1) * sizeof(int));
    int* adj_tut = (int*)alloc((size_t)(E + N) * sizeof(int));
    int* rp_tdt  = (int*)alloc((size_t)(N + 1) * sizeof(int));
    int* adj_tdt = (int*)alloc((size_t)(E + N) * sizeof(int));
    // gcount and gcursor in ONE block (alignment-safe single memset)
    int* gbuf    = (int*)alloc((size_t)4 * NB * sizeof(int));
    int* gcount  = gbuf;
    int* gcursor = gbuf + 2 * NB;
    int* ebase   = (int*)alloc((size_t)2 * (NB + 1) * sizeof(int));
    int* adjbase = (int*)alloc((size_t)2 * (NB + 1) * sizeof(int));
    (void)ws_size; (void)n_in; (void)out_size;

    int2* ebuf = (int2*)hWf;             // alias: ebuf dead before first GEMM writes hWf
    unsigned short* t2hi = xhi;          // alias: x dead after proj GEMM
    unsigned short* zhi  = l1hi;         // z written by fused TDT-L2 gat
    unsigned short* zlo  = l1lo;
    float*          hc   = (float*)hWf;

    const int nodeBlocks = (N + 3) / 4;

    // --------------------- CSR build (bucketed sort) ------------------
    hipMemsetAsync(gbuf, 0, (size_t)4 * NB * sizeof(int), stream);
    prep_kernel<<<1024, 256, 0, stream>>>(proj_W, tut_W, tdt_W, cls_W1,
                                          pWthi, pWtlo, tWthi, tWtlo, dWthi, dWtlo,
                                          cWthi, cWtlo, x, xhi, xlo, (int)(NI / 4));
    bucket_count_kernel<<<dim3(128, 2), 256, 0, stream>>>(tut_ei + E, tdt_ei + E, gcount, E, NB);
    bucket_scan_kernel<<<1, 512, 0, stream>>>(gcount, ebase, adjbase, rp_tut, rp_tdt, N, E, NB);
    bucket_bin_kernel<<<dim3((E + CH - 1) / CH, 2), 256, 0, stream>>>(
        tut_ei, tdt_ei, ebase, gcursor, ebuf, E, NB);
    bucket_csr_kernel<<<dim3(NB, 2), 256, 0, stream>>>(
        gcount, ebase, adjbase, ebuf, rp_tut, rp_tdt, adj_tut, adj_tdt, N, E, NB);

    const int gy = (N + 127) / 128;

    // ------------------------------ proj ------------------------------
    mfma_gemm_kernel<0><<<dim3(2, gy), 256, 0, stream>>>(
        xhi, xlo, pWthi, pWtlo, proj_b, h0hi, h0lo, nullptr, nullptr, N, HID, IN_CH);

    // ---------------------------- GAT layers --------------------------
    auto run_gemm_att = [&](const unsigned short* ahi, const unsigned short* alo,
                            const unsigned short* wthi, const unsigned short* wtlo,
                            const float* asrc_w, const float* adst_w) {
        mfma_gemm_kernel<1><<<dim3(2, gy), 256, 0, stream>>>(
            ahi, alo, wthi, wtlo, nullptr, nullptr, nullptr, hWf, nullptr, N, HID, HID);
        att_kernel<<<nodeBlocks, 256, 0, stream>>>(hWf, asrc_w, adst_w, a_src, a_dst, N);
    };

    const int WT = 256 * 256;
    const int AS = HEADS * (HID / HEADS);

    // TUT layer 1: h0 -> l1
    run_gemm_att(h0hi, h0lo, tWthi, tWtlo, tut_asrc, tut_adst);
    gat_kernel<0><<<nodeBlocks, 256, 0, stream>>>(
        hWf, a_src, a_dst, rp_tut, adj_tut, tut_bias,
        nullptr, nullptr, nullptr, l1hi, l1lo, N);
    // TUT layer 2: l1 -> t2
    run_gemm_att(l1hi, l1lo, tWthi + WT, tWtlo + WT, tut_asrc + AS, tut_adst + AS);
    gat_kernel<0><<<nodeBlocks, 256, 0, stream>>>(
        hWf, a_src, a_dst, rp_tut, adj_tut, tut_bias + HID,
        nullptr, nullptr, nullptr, t2hi, t2lo, N);
    // TDT layer 1: h0 -> l1
    run_gemm_att(h0hi, h0lo, dWthi, dWtlo, tdt_asrc, tdt_adst);
    gat_kernel<0><<<nodeBlocks, 256, 0, stream>>>(
        hWf, a_src, a_dst, rp_tdt, adj_tdt, tdt_bias,
        nullptr, nullptr, nullptr, l1hi, l1lo, N);
    // TDT layer 2 (fused semantic combine): z = w0*t2 + w1*elu(gat)
    run_gemm_att(l1hi, l1lo, dWthi + WT, dWtlo + WT, tdt_asrc + AS, tdt_adst + AS);
    gat_kernel<1><<<nodeBlocks, 256, 0, stream>>>(
        hWf, a_src, a_dst, rp_tdt, adj_tdt, tdt_bias + HID,
        t2hi, t2lo, sem_att, zhi, zlo, N);

    // --------------------------- classifier ---------------------------
    mfma_gemm_kernel<2><<<dim3(1, gy), 256, 0, stream>>>(
        zhi, zlo, cWthi, cWtlo, cls_b1, nullptr, nullptr, nullptr, hc, N, 128, HID);
    cls2_kernel<<<nodeBlocks, 256, 0, stream>>>(hc, cls_W2, cls_b2, (float*)d_out, N);
}

// Round 8
// 738.237 us; speedup vs baseline: 2.3589x; 1.0285x over previous
//
#include <hip/hip_runtime.h>
#include <hip/hip_fp16.h>
#include <cstddef>
#include <cstdint>

// ---------------------------------------------------------------------------
// SimpleHAN on MI355X — round 7:
//   - gat gather restructured: 2 edge-slots x 32 lanes x dwordx4 (16B/lane).
//     One wave-half covers a full 512B row per load instruction: 4x fewer
//     memory instructions, 2 edges in flight, deferred rescale (skip when
//     running max doesn't grow). Softmax phase unchanged.
//   - everything else unchanged from round 6.
// ---------------------------------------------------------------------------

#define HID        256
#define HEADS      8
#define NEG_SLOPE  0.2f

#define BSH     7          // bucket shift: 128 nodes per bucket
#define BNODES  128
#define MAXNB   512        // scan width (NB = 391 for N = 50000)
#define CH      2048       // edges per bin chunk

typedef __attribute__((ext_vector_type(8))) short short8v;
typedef __attribute__((ext_vector_type(4))) float float4v;

static __device__ __forceinline__ unsigned short f32_to_bf16(float v) {
    union { float f; unsigned u; } c; c.f = v;
    unsigned r = c.u + 0x7FFFu + ((c.u >> 16) & 1u);
    return (unsigned short)(r >> 16);
}
static __device__ __forceinline__ float bf16_to_f32(unsigned short b) {
    union { unsigned u; float f; } c; c.u = ((unsigned)b) << 16;
    return c.f;
}
static __device__ __forceinline__ void split_bf16(float v, unsigned short& hi, unsigned short& lo) {
    hi = f32_to_bf16(v);
    lo = f32_to_bf16(v - bf16_to_f32(hi));
}
static __device__ __forceinline__ void gload_lds16(const void* g, void* l) {
    __builtin_amdgcn_global_load_lds((const __attribute__((address_space(1))) void*)g,
                                     (__attribute__((address_space(3))) void*)l, 16, 0, 0);
}

// ------------------------- MFMA GEMM (bf16x3 split) ------------------------
// C[M,N] = (Ahi+Alo)[M,K] @ (Bthi+Btlo)[N,K]^T  (+bias)
// MODE 0: split bf16 hi/lo (+bias). MODE 1: fp16. MODE 2: fp32+bias+relu.
template<int MODE>
__global__ __launch_bounds__(256) void mfma_gemm_kernel(
    const unsigned short* __restrict__ Ahi, const unsigned short* __restrict__ Alo,
    const unsigned short* __restrict__ Bthi, const unsigned short* __restrict__ Btlo,
    const float* __restrict__ bias,
    unsigned short* __restrict__ Chi, unsigned short* __restrict__ Clo,
    __half* __restrict__ Cf16, float* __restrict__ Cf32,
    int M, int N, int K)
{
    __shared__ __align__(16) short lds[4 * 4096];  // 32 KB

    const int tid  = threadIdx.x;
    const int lane = tid & 63;
    const int w    = tid >> 6;
    const int wr   = w >> 1;
    const int wc   = w & 1;
    const int m0   = blockIdx.y * 128;
    const int n0   = blockIdx.x * 128;

    const unsigned short* sbase = (w == 0) ? Ahi : (w == 1) ? Alo : (w == 2) ? Bthi : Btlo;
    const int rowbase = (w < 2) ? m0 : n0;
    const int rowlim  = ((w < 2) ? M : N) - 1;

    float4v acc[4][4];
    #pragma unroll
    for (int i = 0; i < 4; ++i)
        #pragma unroll
        for (int j = 0; j < 4; ++j)
            acc[i][j] = (float4v){0.f, 0.f, 0.f, 0.f};

    const int kcl = lane >> 4;
    const int rl  = lane & 15;

    for (int k0 = 0; k0 < K; k0 += 32) {
        #pragma unroll
        for (int rh = 0; rh < 2; ++rh) {
            int row = rowbase + rh * 64 + lane;
            row = row > rowlim ? rowlim : row;
            const unsigned short* src = sbase + (size_t)row * K + k0;
            #pragma unroll
            for (int kc = 0; kc < 4; ++kc) {
                short* dst = &lds[w * 4096 + kc * 1024 + rh * 512];
                gload_lds16(src + kc * 8, dst);
            }
        }
        __syncthreads();

        short8v ahi[4], alo[4], bhi[4], blo[4];
        #pragma unroll
        for (int i = 0; i < 4; ++i) {
            int am = wr * 64 + i * 16 + rl;
            int bn = wc * 64 + i * 16 + rl;
            ahi[i] = *(const short8v*)&lds[0 * 4096 + kcl * 1024 + am * 8];
            alo[i] = *(const short8v*)&lds[1 * 4096 + kcl * 1024 + am * 8];
            bhi[i] = *(const short8v*)&lds[2 * 4096 + kcl * 1024 + bn * 8];
            blo[i] = *(const short8v*)&lds[3 * 4096 + kcl * 1024 + bn * 8];
        }
        #pragma unroll
        for (int i = 0; i < 4; ++i)
            #pragma unroll
            for (int j = 0; j < 4; ++j) {
                acc[i][j] = __builtin_amdgcn_mfma_f32_16x16x32_bf16(ahi[i], bhi[j], acc[i][j], 0, 0, 0);
                acc[i][j] = __builtin_amdgcn_mfma_f32_16x16x32_bf16(ahi[i], blo[j], acc[i][j], 0, 0, 0);
                acc[i][j] = __builtin_amdgcn_mfma_f32_16x16x32_bf16(alo[i], bhi[j], acc[i][j], 0, 0, 0);
            }
        __syncthreads();
    }

    const int cr = (lane >> 4) * 4;
    #pragma unroll
    for (int i = 0; i < 4; ++i) {
        #pragma unroll
        for (int r = 0; r < 4; ++r) {
            int row = m0 + wr * 64 + i * 16 + cr + r;
            if (row >= M) continue;
            #pragma unroll
            for (int j = 0; j < 4; ++j) {
                int col = n0 + wc * 64 + j * 16 + rl;
                float v = acc[i][j][r];
                if (bias) v += bias[col];
                if (MODE == 0) {
                    unsigned short h, l;
                    split_bf16(v, h, l);
                    Chi[(size_t)row * N + col] = h;
                    Clo[(size_t)row * N + col] = l;
                } else if (MODE == 1) {
                    Cf16[(size_t)row * N + col] = __float2half(v);
                } else {
                    Cf32[(size_t)row * N + col] = fmaxf(v, 0.f);
                }
            }
        }
    }
}

// ----------------------- unified prep (weights + x) ------------------------
__global__ void prep_kernel(
    const float* __restrict__ proj_W, const float* __restrict__ tut_W,
    const float* __restrict__ tdt_W, const float* __restrict__ cls_W1,
    unsigned short* __restrict__ pWthi, unsigned short* __restrict__ pWtlo,
    unsigned short* __restrict__ tWthi, unsigned short* __restrict__ tWtlo,
    unsigned short* __restrict__ dWthi, unsigned short* __restrict__ dWtlo,
    unsigned short* __restrict__ cWthi, unsigned short* __restrict__ cWtlo,
    const float* __restrict__ x,
    unsigned short* __restrict__ xhi, unsigned short* __restrict__ xlo, int count4x)
{
    const int tid = blockIdx.x * blockDim.x + threadIdx.x;
    const int stride = gridDim.x * blockDim.x;
    for (int idx = tid; idx < 327680; idx += stride) {
        unsigned short h, l;
        if (idx < 32768) {
            int k = idx >> 8, n = idx & 255;
            split_bf16(proj_W[idx], h, l);
            pWthi[n * 128 + k] = h; pWtlo[n * 128 + k] = l;
        } else if (idx < 163840) {
            int r = idx - 32768;
            int ly = r >> 16, rr = r & 65535;
            int k = rr >> 8, n = rr & 255;
            split_bf16(tut_W[r], h, l);
            tWthi[ly * 65536 + n * 256 + k] = h; tWtlo[ly * 65536 + n * 256 + k] = l;
        } else if (idx < 294912) {
            int r = idx - 163840;
            int ly = r >> 16, rr = r & 65535;
            int k = rr >> 8, n = rr & 255;
            split_bf16(tdt_W[r], h, l);
            dWthi[ly * 65536 + n * 256 + k] = h; dWtlo[ly * 65536 + n * 256 + k] = l;
        } else {
            int r = idx - 294912;
            int k = r >> 7, n = r & 127;
            split_bf16(cls_W1[r], h, l);
            cWthi[n * 256 + k] = h; cWtlo[n * 256 + k] = l;
        }
    }
    for (int i = tid; i < count4x; i += stride) {
        float4 v = reinterpret_cast<const float4*>(x)[i];
        ushort4 hh, ll;
        split_bf16(v.x, hh.x, ll.x);
        split_bf16(v.y, hh.y, ll.y);
        split_bf16(v.z, hh.z, ll.z);
        split_bf16(v.w, hh.w, ll.w);
        reinterpret_cast<ushort4*>(xhi)[i] = hh;
        reinterpret_cast<ushort4*>(xlo)[i] = ll;
    }
}

// ------------------------- attention dot products --------------------------
__global__ __launch_bounds__(256) void att_kernel(
    const __half* __restrict__ hW,
    const float* __restrict__ att_src, const float* __restrict__ att_dst,
    float* __restrict__ a_src, float* __restrict__ a_dst, int n_nodes)
{
    const int wave = threadIdx.x >> 6;
    const int lane = threadIdx.x & 63;
    const int n = blockIdx.x * 4 + wave;
    if (n >= n_nodes) return;

    const __half2* hp = reinterpret_cast<const __half2*>(&hW[(size_t)n * HID + lane * 4]);
    __half2 h01 = hp[0], h23 = hp[1];
    float hx = __low2float(h01), hy = __high2float(h01);
    float hz = __low2float(h23), hw = __high2float(h23);
    float4 s4 = *reinterpret_cast<const float4*>(&att_src[lane * 4]);
    float4 d4 = *reinterpret_cast<const float4*>(&att_dst[lane * 4]);
    float ps = hx * s4.x + hy * s4.y + hz * s4.z + hw * s4.w;
    float pd = hx * d4.x + hy * d4.y + hz * d4.z + hw * d4.w;
    #pragma unroll
    for (int off = 1; off < 8; off <<= 1) {
        ps += __shfl_xor(ps, off);
        pd += __shfl_xor(pd, off);
    }
    if ((lane & 7) == 0) {
        a_src[n * HEADS + (lane >> 3)] = ps;
        a_dst[n * HEADS + (lane >> 3)] = pd;
    }
}

// ----------------- GAT single-pass online softmax + gather -----------------
// Softmax lanes: head h2=lane>>3 x slot sl=lane&7 (p for edge j+jj, head h
// lives at lane h*8+jj). Gather lanes: half-wave hw=lane>>5 is edge parity;
// lane covers dims d0=(lane&31)*8 (head hd=d0>>5); alpha/scale/inv shfl'd
// from lane hd*8+jj. One dwordx4 (16B) per lane per edge -> a 32-lane half
// covers the full 512B row in one instruction. Final merge: shfl_xor(32).
template<int OMODE>
__global__ __launch_bounds__(256) void gat_kernel(
    const __half* __restrict__ hW,
    const float* __restrict__ a_src, const float* __restrict__ a_dst,
    const int* __restrict__ row_ptr, const int* __restrict__ adj,
    const float* __restrict__ bias,
    const unsigned short* __restrict__ prevHi, const unsigned short* __restrict__ prevLo,
    const float* __restrict__ sem,
    unsigned short* __restrict__ outhi, unsigned short* __restrict__ outlo,
    int n_nodes)
{
    const int wave = threadIdx.x >> 6;
    const int lane = threadIdx.x & 63;
    const int n = blockIdx.x * 4 + wave;
    if (n >= n_nodes) return;

    const int beg = row_ptr[n];
    const int end = row_ptr[n + 1];
    const int h2 = lane >> 3;          // softmax head
    const int sl = lane & 7;           // softmax edge slot
    const int hw = lane >> 5;          // gather edge parity
    const int l32 = lane & 31;
    const int d0 = l32 * 8;            // gather dims d0..d0+7
    const int ah = (l32 >> 2) * 8;     // alpha-source lane base (head(d0)*8)

    const float adst = a_dst[n * HEADS + h2];

    float m = -INFINITY, s = 0.f;
    float acc[8];
    #pragma unroll
    for (int k = 0; k < 8; ++k) acc[k] = 0.f;

    for (int j = beg; j < end; j += 8) {
        // ---- online softmax over the 8-edge group (per head) ----
        const int js = j + sl;
        const int valid = js < end;
        int src_l = valid ? adj[js] : 0;
        float e = -INFINITY;
        if (valid) {
            e = a_src[src_l * HEADS + h2] + adst;
            e = (e > 0.f) ? e : NEG_SLOPE * e;
        }
        float me = e;
        me = fmaxf(me, __shfl_xor(me, 1));
        me = fmaxf(me, __shfl_xor(me, 2));
        me = fmaxf(me, __shfl_xor(me, 4));
        const float m_new = fmaxf(m, me);
        const float p = __expf(e - m_new);       // 0 for invalid slots
        float ps = p;
        ps += __shfl_xor(ps, 1);
        ps += __shfl_xor(ps, 2);
        ps += __shfl_xor(ps, 4);
        if (__any(m_new > m)) {                  // deferred rescale (wave-uniform)
            const float scale = __expf(m - m_new);
            const float scale_g = __shfl(scale, ah);
            s *= scale;
            #pragma unroll
            for (int k = 0; k < 8; ++k) acc[k] *= scale_g;
            m = m_new;
        }
        s += ps;

        // ---- gather: 2 edges per iteration, 16B/lane ----
        #pragma unroll
        for (int it = 0; it < 4; ++it) {
            const int jj = it * 2 + hw;
            const float alpha = __shfl(p, ah | jj);
            const int srce = __shfl(src_l, jj);
            if (j + jj < end) {
                float4 raw = *reinterpret_cast<const float4*>(&hW[(size_t)srce * HID + d0]);
                __half2 v0 = *reinterpret_cast<__half2*>(&raw.x);
                __half2 v1 = *reinterpret_cast<__half2*>(&raw.y);
                __half2 v2 = *reinterpret_cast<__half2*>(&raw.z);
                __half2 v3 = *reinterpret_cast<__half2*>(&raw.w);
                acc[0] += alpha * __low2float(v0); acc[1] += alpha * __high2float(v0);
                acc[2] += alpha * __low2float(v1); acc[3] += alpha * __high2float(v1);
                acc[4] += alpha * __low2float(v2); acc[5] += alpha * __high2float(v2);
                acc[6] += alpha * __low2float(v3); acc[7] += alpha * __high2float(v3);
            }
        }
    }

    // merge the two edge-parity halves
    #pragma unroll
    for (int k = 0; k < 8; ++k) acc[k] += __shfl_xor(acc[k], 32);

    const float inv = 1.f / (s + 1e-16f);        // valid per softmax lane
    const float inv_g = __shfl(inv, ah);

    if (lane < 32) {
        float4 b0 = *reinterpret_cast<const float4*>(&bias[d0]);
        float4 b1 = *reinterpret_cast<const float4*>(&bias[d0 + 4]);
        float o[8];
        o[0] = acc[0] * inv_g + b0.x; o[1] = acc[1] * inv_g + b0.y;
        o[2] = acc[2] * inv_g + b0.z; o[3] = acc[3] * inv_g + b0.w;
        o[4] = acc[4] * inv_g + b1.x; o[5] = acc[5] * inv_g + b1.y;
        o[6] = acc[6] * inv_g + b1.z; o[7] = acc[7] * inv_g + b1.w;
        #pragma unroll
        for (int k = 0; k < 8; ++k)
            o[k] = (o[k] > 0.f) ? o[k] : expm1f(o[k]);

        if (OMODE == 1) {
            const float e0 = __expf(sem[0]);
            const float e1 = __expf(sem[1]);
            const float w0 = e0 / (e0 + e1);
            const float w1 = e1 / (e0 + e1);
            ushort4 ph0 = *reinterpret_cast<const ushort4*>(&prevHi[(size_t)n * HID + d0]);
            ushort4 ph1 = *reinterpret_cast<const ushort4*>(&prevHi[(size_t)n * HID + d0 + 4]);
            ushort4 pl0 = *reinterpret_cast<const ushort4*>(&prevLo[(size_t)n * HID + d0]);
            ushort4 pl1 = *reinterpret_cast<const ushort4*>(&prevLo[(size_t)n * HID + d0 + 4]);
            o[0] = w0 * (bf16_to_f32(ph0.x) + bf16_to_f32(pl0.x)) + w1 * o[0];
            o[1] = w0 * (bf16_to_f32(ph0.y) + bf16_to_f32(pl0.y)) + w1 * o[1];
            o[2] = w0 * (bf16_to_f32(ph0.z) + bf16_to_f32(pl0.z)) + w1 * o[2];
            o[3] = w0 * (bf16_to_f32(ph0.w) + bf16_to_f32(pl0.w)) + w1 * o[3];
            o[4] = w0 * (bf16_to_f32(ph1.x) + bf16_to_f32(pl1.x)) + w1 * o[4];
            o[5] = w0 * (bf16_to_f32(ph1.y) + bf16_to_f32(pl1.y)) + w1 * o[5];
            o[6] = w0 * (bf16_to_f32(ph1.z) + bf16_to_f32(pl1.z)) + w1 * o[6];
            o[7] = w0 * (bf16_to_f32(ph1.w) + bf16_to_f32(pl1.w)) + w1 * o[7];
        }

        ushort4 oh0, oh1, ol0, ol1;
        split_bf16(o[0], oh0.x, ol0.x); split_bf16(o[1], oh0.y, ol0.y);
        split_bf16(o[2], oh0.z, ol0.z); split_bf16(o[3], oh0.w, ol0.w);
        split_bf16(o[4], oh1.x, ol1.x); split_bf16(o[5], oh1.y, ol1.y);
        split_bf16(o[6], oh1.z, ol1.z); split_bf16(o[7], oh1.w, ol1.w);
        *reinterpret_cast<ushort4*>(&outhi[(size_t)n * HID + d0])     = oh0;
        *reinterpret_cast<ushort4*>(&outhi[(size_t)n * HID + d0 + 4]) = oh1;
        *reinterpret_cast<ushort4*>(&outlo[(size_t)n * HID + d0])     = ol0;
        *reinterpret_cast<ushort4*>(&outlo[(size_t)n * HID + d0 + 4]) = ol1;
    }
}

// ------------------- CSR build: bucketed counting sort ---------------------
__global__ __launch_bounds__(256) void bucket_count_kernel(
    const int* __restrict__ tut_dst, const int* __restrict__ tdt_dst,
    int* __restrict__ gcount, int E, int NB)
{
    __shared__ int hist[MAXNB];
    const int g = blockIdx.y;
    const int* dstp = g ? tdt_dst : tut_dst;
    for (int i = threadIdx.x; i < MAXNB; i += 256) hist[i] = 0;
    __syncthreads();
    for (int e = blockIdx.x * 256 + threadIdx.x; e < E; e += gridDim.x * 256)
        atomicAdd(&hist[dstp[e] >> BSH], 1);
    __syncthreads();
    for (int i = threadIdx.x; i < NB; i += 256) {
        int c = hist[i];
        if (c) atomicAdd(&gcount[g * NB + i], c);
    }
}

__global__ __launch_bounds__(512) void bucket_scan_kernel(
    const int* __restrict__ gcount, int* __restrict__ ebase, int* __restrict__ adjbase,
    int* __restrict__ rp0, int* __restrict__ rp1, int N, int E, int NB)
{
    __shared__ int sa[MAXNB], sb[MAXNB];
    const int t = threadIdx.x;
    for (int g = 0; g < 2; ++g) {
        int cnt = (t < NB) ? gcount[g * NB + t] : 0;
        int nodes = 0;
        if (t < NB) { int s = t << BSH; nodes = (N - s < BNODES) ? (N - s) : BNODES; }
        sa[t] = cnt;
        sb[t] = cnt + nodes;
        __syncthreads();
        for (int off = 1; off < MAXNB; off <<= 1) {
            int va = (t >= off) ? sa[t - off] : 0;
            int vb = (t >= off) ? sb[t - off] : 0;
            __syncthreads();
            sa[t] += va; sb[t] += vb;
            __syncthreads();
        }
        if (t < NB) {
            ebase[g * (NB + 1) + t + 1] = sa[t];
            adjbase[g * (NB + 1) + t + 1] = sb[t];
        }
        if (t == 0) { ebase[g * (NB + 1)] = 0; adjbase[g * (NB + 1)] = 0; }
        __syncthreads();
    }
    if (t == 0) { rp0[N] = E + N; rp1[N] = E + N; }
}

__global__ __launch_bounds__(256) void bucket_bin_kernel(
    const int* __restrict__ tut_ei, const int* __restrict__ tdt_ei,
    const int* __restrict__ ebase, int* __restrict__ gcursor,
    int2* __restrict__ ebuf, int E, int NB)
{
    __shared__ int lhist[MAXNB];
    __shared__ int lbase[MAXNB];
    __shared__ int loffs[MAXNB];
    __shared__ int2 spair[CH];
    __shared__ int saddr[CH];
    const int g = blockIdx.y;
    const int* ei = g ? tdt_ei : tut_ei;
    const int e0 = blockIdx.x * CH;
    const int cnt = (E - e0 < CH) ? (E - e0) : CH;

    for (int i = threadIdx.x; i < MAXNB; i += 256) lhist[i] = 0;
    __syncthreads();

    int myb[8], myrank[8], mysrc[8], mydst[8];
    int nmine = 0;
    #pragma unroll
    for (int k = 0; k < 8; ++k) {
        int idx = e0 + threadIdx.x + k * 256;
        if (idx < e0 + cnt) {
            int sv = ei[idx];
            int dv = ei[E + idx];
            int b = dv >> BSH;
            int r = atomicAdd(&lhist[b], 1);
            myb[nmine] = b; myrank[nmine] = r; mysrc[nmine] = sv; mydst[nmine] = dv;
            ++nmine;
        }
    }
    __syncthreads();
    loffs[threadIdx.x] = lhist[threadIdx.x];
    loffs[threadIdx.x + 256] = lhist[threadIdx.x + 256];
    __syncthreads();
    for (int off = 1; off < MAXNB; off <<= 1) {
        int i0 = threadIdx.x, i1 = threadIdx.x + 256;
        int v0 = (i0 >= off) ? loffs[i0 - off] : 0;
        int v1 = (i1 >= off) ? loffs[i1 - off] : 0;
        __syncthreads();
        loffs[i0] += v0; loffs[i1] += v1;
        __syncthreads();
    }
    for (int i = threadIdx.x; i < NB; i += 256) {
        int c = lhist[i];
        lbase[i] = c ? atomicAdd(&gcursor[g * NB + i], c) : 0;
    }
    __syncthreads();
    const int* eb = ebase + g * (NB + 1);
    for (int k = 0; k < nmine; ++k) {
        int b = myb[k];
        int sorted = loffs[b] - lhist[b] + myrank[k];
        spair[sorted] = make_int2(mysrc[k], mydst[k]);
        saddr[sorted] = eb[b] + lbase[b] + myrank[k];
    }
    __syncthreads();
    int2* out = ebuf + (size_t)g * E;
    for (int i = threadIdx.x; i < cnt; i += 256)
        out[saddr[i]] = spair[i];
}

__global__ __launch_bounds__(256) void bucket_csr_kernel(
    const int* __restrict__ gcount, const int* __restrict__ ebase,
    const int* __restrict__ adjbase, const int2* __restrict__ ebuf,
    int* __restrict__ rp0, int* __restrict__ rp1,
    int* __restrict__ adj0, int* __restrict__ adj1, int N, int E, int NB)
{
    __shared__ int hist[BNODES], scn[BNODES], cursor[BNODES];
    const int g = blockIdx.y;
    const int b = blockIdx.x;
    int* rp  = g ? rp1 : rp0;
    int* adj = g ? adj1 : adj0;
    const int cnt = gcount[g * NB + b];
    const int aB  = adjbase[g * (NB + 1) + b];
    const int node0 = b << BSH;
    const int nb = (N - node0 < BNODES) ? (N - node0) : BNODES;
    const int2* ep = ebuf + (size_t)g * E + ebase[g * (NB + 1) + b];
    const int t = threadIdx.x;

    if (t < BNODES) hist[t] = 0;
    __syncthreads();
    for (int e = t; e < cnt; e += 256)
        atomicAdd(&hist[ep[e].y - node0], 1);
    __syncthreads();
    if (t < BNODES) scn[t] = (t < nb) ? hist[t] + 1 : 0;
    __syncthreads();
    for (int off = 1; off < BNODES; off <<= 1) {
        int v = 0;
        if (t < BNODES && t >= off) v = scn[t - off];
        __syncthreads();
        if (t < BNODES) scn[t] += v;
        __syncthreads();
    }
    if (t < nb) {
        int s = scn[t] - hist[t] - 1;       // exclusive offset
        rp[node0 + t] = aB + s;
        adj[aB + s] = node0 + t;            // self-loop first
        cursor[t] = s + 1;
    }
    __syncthreads();
    for (int e = t; e < cnt; e += 256) {
        int2 pr = ep[e];
        int pos = atomicAdd(&cursor[pr.y - node0], 1);
        adj[aB + pos] = pr.x;
    }
}

// ------------------------------- classifier --------------------------------
__global__ __launch_bounds__(256) void cls2_kernel(
    const float* __restrict__ hc, const float* __restrict__ W2,
    const float* __restrict__ b2, float* __restrict__ out, int n_nodes)
{
    const int wave = threadIdx.x >> 6;
    const int lane = threadIdx.x & 63;
    const int n = blockIdx.x * 4 + wave;
    if (n >= n_nodes) return;
    float h0 = hc[(size_t)n * 128 + lane];
    float h1 = hc[(size_t)n * 128 + 64 + lane];
    float p0 = h0 * W2[lane * 2 + 0] + h1 * W2[(64 + lane) * 2 + 0];
    float p1 = h0 * W2[lane * 2 + 1] + h1 * W2[(64 + lane) * 2 + 1];
    #pragma unroll
    for (int off = 1; off < 64; off <<= 1) {
        p0 += __shfl_xor(p0, off);
        p1 += __shfl_xor(p1, off);
    }
    if (lane == 0) {
        out[(size_t)n * 2 + 0] = p0 + b2[0];
        out[(size_t)n * 2 + 1] = p1 + b2[1];
    }
}

// ---------------------------------------------------------------------------
extern "C" void kernel_launch(void* const* d_in, const int* in_sizes, int n_in,
                              void* d_out, int out_size, void* d_ws, size_t ws_size,
                              hipStream_t stream)
{
    const float* x        = (const float*)d_in[0];
    const int*   tut_ei   = (const int*)d_in[1];
    const int*   tdt_ei   = (const int*)d_in[2];
    const float* proj_W   = (const float*)d_in[3];
    const float* proj_b   = (const float*)d_in[4];
    const float* tut_W    = (const float*)d_in[5];
    const float* tut_asrc = (const float*)d_in[6];
    const float* tut_adst = (const float*)d_in[7];
    const float* tut_bias = (const float*)d_in[8];
    const float* tdt_W    = (const float*)d_in[9];
    const float* tdt_asrc = (const float*)d_in[10];
    const float* tdt_adst = (const float*)d_in[11];
    const float* tdt_bias = (const float*)d_in[12];
    const float* sem_att  = (const float*)d_in[13];
    const float* cls_W1   = (const float*)d_in[14];
    const float* cls_b1   = (const float*)d_in[15];
    const float* cls_W2   = (const float*)d_in[16];
    const float* cls_b2   = (const float*)d_in[17];

    const int IN_CH = 128;
    const int N = in_sizes[0] / IN_CH;     // 50000
    const int E = in_sizes[1] / 2;         // 800000
    const int NB = (N + BNODES - 1) >> BSH; // 391
    const size_t NH = (size_t)N * HID;
    const size_t NI = (size_t)N * IN_CH;

    // ------------------------ workspace layout ------------------------
    char* base = (char*)d_ws;
    size_t off = 0;
    auto alloc = [&](size_t bytes) -> void* {
        void* p = base + off;
        off = (off + bytes + 255) & ~(size_t)255;
        return p;
    };
    unsigned short* xhi  = (unsigned short*)alloc(NI * 2);
    unsigned short* xlo  = (unsigned short*)alloc(NI * 2);
    unsigned short* t2lo = (unsigned short*)alloc(NH * 2);
    unsigned short* h0hi = (unsigned short*)alloc(NH * 2);
    unsigned short* h0lo = (unsigned short*)alloc(NH * 2);
    unsigned short* l1hi = (unsigned short*)alloc(NH * 2);
    unsigned short* l1lo = (unsigned short*)alloc(NH * 2);
    __half*         hWf  = (__half*)alloc(NH * 2);           // 25.6MB; ebuf aliases
    float* a_src = (float*)alloc((size_t)N * HEADS * sizeof(float));
    float* a_dst = (float*)alloc((size_t)N * HEADS * sizeof(float));
    unsigned short* pWthi = (unsigned short*)alloc(256 * 128 * 2);
    unsigned short* pWtlo = (unsigned short*)alloc(256 * 128 * 2);
    unsigned short* tWthi = (unsigned short*)alloc(2 * 256 * 256 * 2);
    unsigned short* tWtlo = (unsigned short*)alloc(2 * 256 * 256 * 2);
    unsigned short* dWthi = (unsigned short*)alloc(2 * 256 * 256 * 2);
    unsigned short* dWtlo = (unsigned short*)alloc(2 * 256 * 256 * 2);
    unsigned short* cWthi = (unsigned short*)alloc(128 * 256 * 2);
    unsigned short* cWtlo = (unsigned short*)alloc(128 * 256 * 2);
    int* rp_tut  = (int*)alloc((size_t)(N + 1) * sizeof(int));
    int* adj_tut = (int*)alloc((size_t)(E + N) * sizeof(int));
    int* rp_tdt  = (int*)alloc((size_t)(N + 1) * sizeof(int));
    int* adj_tdt = (int*)alloc((size_t)(E + N) * sizeof(int));
    // gcount and gcursor in ONE block (alignment-safe single memset)
    int* gbuf    = (int*)alloc((size_t)4 * NB * sizeof(int));
    int* gcount  = gbuf;
    int* gcursor = gbuf + 2 * NB;
    int* ebase   = (int*)alloc((size_t)2 * (NB + 1) * sizeof(int));
    int* adjbase = (int*)alloc((size_t)2 * (NB + 1) * sizeof(int));
    (void)ws_size; (void)n_in; (void)out_size;

    int2* ebuf = (int2*)hWf;             // alias: ebuf dead before first GEMM writes hWf
    unsigned short* t2hi = xhi;          // alias: x dead after proj GEMM
    unsigned short* zhi  = l1hi;         // z written by fused TDT-L2 gat
    unsigned short* zlo  = l1lo;
    float*          hc   = (float*)hWf;

    const int nodeBlocks = (N + 3) / 4;

    // --------------------- CSR build (bucketed sort) ------------------
    hipMemsetAsync(gbuf, 0, (size_t)4 * NB * sizeof(int), stream);
    prep_kernel<<<1024, 256, 0, stream>>>(proj_W, tut_W, tdt_W, cls_W1,
                                          pWthi, pWtlo, tWthi, tWtlo, dWthi, dWtlo,
                                          cWthi, cWtlo, x, xhi, xlo, (int)(NI / 4));
    bucket_count_kernel<<<dim3(128, 2), 256, 0, stream>>>(tut_ei + E, tdt_ei + E, gcount, E, NB);
    bucket_scan_kernel<<<1, 512, 0, stream>>>(gcount, ebase, adjbase, rp_tut, rp_tdt, N, E, NB);
    bucket_bin_kernel<<<dim3((E + CH - 1) / CH, 2), 256, 0, stream>>>(
        tut_ei, tdt_ei, ebase, gcursor, ebuf, E, NB);
    bucket_csr_kernel<<<dim3(NB, 2), 256, 0, stream>>>(
        gcount, ebase, adjbase, ebuf, rp_tut, rp_tdt, adj_tut, adj_tdt, N, E, NB);

    const int gy = (N + 127) / 128;

    // ------------------------------ proj ------------------------------
    mfma_gemm_kernel<0><<<dim3(2, gy), 256, 0, stream>>>(
        xhi, xlo, pWthi, pWtlo, proj_b, h0hi, h0lo, nullptr, nullptr, N, HID, IN_CH);

    // ---------------------------- GAT layers --------------------------
    auto run_gemm_att = [&](const unsigned short* ahi, const unsigned short* alo,
                            const unsigned short* wthi, const unsigned short* wtlo,
                            const float* asrc_w, const float* adst_w) {
        mfma_gemm_kernel<1><<<dim3(2, gy), 256, 0, stream>>>(
            ahi, alo, wthi, wtlo, nullptr, nullptr, nullptr, hWf, nullptr, N, HID, HID);
        att_kernel<<<nodeBlocks, 256, 0, stream>>>(hWf, asrc_w, adst_w, a_src, a_dst, N);
    };

    const int WT = 256 * 256;
    const int AS = HEADS * (HID / HEADS);

    // TUT layer 1: h0 -> l1
    run_gemm_att(h0hi, h0lo, tWthi, tWtlo, tut_asrc, tut_adst);
    gat_kernel<0><<<nodeBlocks, 256, 0, stream>>>(
        hWf, a_src, a_dst, rp_tut, adj_tut, tut_bias,
        nullptr, nullptr, nullptr, l1hi, l1lo, N);
    // TUT layer 2: l1 -> t2
    run_gemm_att(l1hi, l1lo, tWthi + WT, tWtlo + WT, tut_asrc + AS, tut_adst + AS);
    gat_kernel<0><<<nodeBlocks, 256, 0, stream>>>(
        hWf, a_src, a_dst, rp_tut, adj_tut, tut_bias + HID,
        nullptr, nullptr, nullptr, t2hi, t2lo, N);
    // TDT layer 1: h0 -> l1
    run_gemm_att(h0hi, h0lo, dWthi, dWtlo, tdt_asrc, tdt_adst);
    gat_kernel<0><<<nodeBlocks, 256, 0, stream>>>(
        hWf, a_src, a_dst, rp_tdt, adj_tdt, tdt_bias,
        nullptr, nullptr, nullptr, l1hi, l1lo, N);
    // TDT layer 2 (fused semantic combine): z = w0*t2 + w1*elu(gat)
    run_gemm_att(l1hi, l1lo, dWthi + WT, dWtlo + WT, tdt_asrc + AS, tdt_adst + AS);
    gat_kernel<1><<<nodeBlocks, 256, 0, stream>>>(
        hWf, a_src, a_dst, rp_tdt, adj_tdt, tdt_bias + HID,
        t2hi, t2lo, sem_att, zhi, zlo, N);

    // --------------------------- classifier ---------------------------
    mfma_gemm_kernel<2><<<dim3(1, gy), 256, 0, stream>>>(
        zhi, zlo, cWthi, cWtlo, cls_b1, nullptr, nullptr, nullptr, hc, N, 128, HID);
    cls2_kernel<<<nodeBlocks, 256, 0, stream>>>(hc, cls_W2, cls_b2, (float*)d_out, N);
}